// Round 1
// baseline (549.803 us; speedup 1.0000x reference)
//
#include <hip/hip_runtime.h>
#include <hip/hip_bf16.h>
#include <stdint.h>

// Problem constants
#define NB 8192     // B
#define NL 16       // L
#define NS 256      // S
#define NT 1000     // T
#define NC 500      // C
#define NS5 1280    // 5*S
#define NROWS_JC (NB*15)   // 122880 join rows / inputx rows

typedef __attribute__((ext_vector_type(8))) short bf16x8;
typedef __attribute__((ext_vector_type(4))) float f32x4;

typedef __attribute__((address_space(1))) const void gas_void;
typedef __attribute__((address_space(3))) void las_void;

__device__ __forceinline__ void g2l16(const void* g, void* l) {
  __builtin_amdgcn_global_load_lds((gas_void*)g, (las_void*)l, 16, 0, 0);
}

__device__ __forceinline__ float sigf(float x) { return 1.f / (1.f + __expf(-x)); }
__device__ __forceinline__ float tanhfast(float x) {
  float e = __expf(2.f * fabsf(x));
  float t = 1.f - 2.f / (e + 1.f);
  return copysignf(t, x);
}
__device__ __forceinline__ unsigned short bf16b(float x) {
  __hip_bfloat16 h = __float2bfloat16(x);
  return *reinterpret_cast<unsigned short*>(&h);
}

// Gate-interleaved packed-column decode.
// packed col pc = slice*320 + wcol*160 + (g*2+h2)*16 + u16
//   -> unit U = slice*64 + wcol*32 + h2*16 + u16, gate g, orig col = g*256 + U
__device__ __forceinline__ int origcol(int slice, int nc) {
  int wcol = nc / 160, rem = nc % 160;
  int t = rem >> 4, u16 = rem & 15;
  int g = t >> 1, h2 = t & 1;
  int U = slice * 64 + wcol * 32 + h2 * 16 + u16;
  return g * 256 + U;
}

// ---------------- LayerNorm of the embedding table ----------------
__global__ __launch_bounds__(256) void ln_kernel(
    const float* __restrict__ emb, const float* __restrict__ g,
    const float* __restrict__ b, float* __restrict__ of32,
    unsigned short* __restrict__ ob16) {
  int t = blockIdx.x;
  int i = threadIdx.x;
  int lane = i & 63, wv = i >> 6;
  float x = emb[t * NS + i];
  float s = x, s2 = x * x;
  for (int o = 1; o < 64; o <<= 1) {
    s += __shfl_xor(s, o);
    s2 += __shfl_xor(s2, o);
  }
  __shared__ float rs[4], rs2[4];
  if (lane == 0) { rs[wv] = s; rs2[wv] = s2; }
  __syncthreads();
  float S = rs[0] + rs[1] + rs[2] + rs[3];
  float S2 = rs2[0] + rs2[1] + rs2[2] + rs2[3];
  float mu = S * (1.f / NS);
  float var = S2 * (1.f / NS) - mu * mu;
  float y = (x - mu) * rsqrtf(var + 1e-5f) * g[i] + b[i];
  of32[t * NS + i] = y;
  ob16[t * NS + i] = bf16b(y);
}

// ---------------- Pack [W1;W2;W0] into per-K-chunk swizzled LDS images ----------------
// image: [slice(4)][kc(24)][20480 bytes]; within chunk: value (nc,kk) at byte
//   nc*64 + ((kk>>3) ^ ((nc>>1)&3))*16 + (kk&7)*2
__global__ __launch_bounds__(256) void pack_w12(
    const float* __restrict__ W1, const float* __restrict__ W2,
    const float* __restrict__ W0, unsigned short* __restrict__ out) {
  int e = blockIdx.x * 256 + threadIdx.x;  // 4*24*320*32 = 983040
  if (e >= 4 * 24 * 320 * 32) return;
  int kk = e & 31;
  int r = e >> 5;
  int nc = r % 320; r /= 320;
  int kc = r % 24;
  int slice = r / 24;
  int k = kc * 32 + kk;
  int oc = origcol(slice, nc);
  float v;
  if (k < 256) v = W1[(size_t)k * NS5 + oc];
  else if (k < 512) v = W2[(size_t)(k - 256) * NS5 + oc];
  else v = W0[(size_t)(k - 512) * NS5 + oc];
  size_t dst = (size_t)(slice * 24 + kc) * 20480 + nc * 64 +
               (((kk >> 3) ^ ((nc >> 1) & 3)) << 4) + (kk & 7) * 2;
  *(unsigned short*)((char*)out + dst) = bf16b(v);
}

// ---------------- Combined z-bias (b1+b2+b0 + jc_b@W0), packed columns ----------------
__global__ __launch_bounds__(256) void bias_kernel(
    const float* __restrict__ b1, const float* __restrict__ b2,
    const float* __restrict__ b0, const float* __restrict__ jcb,
    const float* __restrict__ W0, float* __restrict__ bias_zp) {
  int pc = blockIdx.x * 256 + threadIdx.x;
  if (pc >= NS5) return;
  int slice = pc / 320, nc = pc % 320;
  int oc = origcol(slice, nc);
  float s = b1[oc] + b2[oc] + b0[oc];
  for (int k = 0; k < NS; ++k) s += jcb[k] * W0[(size_t)k * NS5 + oc];
  bias_zp[pc] = s;
}

// ---------------- Sparse join: inputx = join_cols @ jc_W  (binary jc, ~1% ones) ----------------
__global__ __launch_bounds__(256) void inputx_kernel(
    const float* __restrict__ jc, const float* __restrict__ jcW,
    unsigned short* __restrict__ outp) {
  int wv = threadIdx.x >> 6, lane = threadIdx.x & 63;
  size_t row = (size_t)blockIdx.x * 4 + wv;  // < 122880
  const float* jr = jc + row * NC;
  float a0 = 0, a1 = 0, a2 = 0, a3 = 0;
  for (int c0 = 0; c0 < NC; c0 += 64) {
    int idx = c0 + lane;
    float v = (idx < NC) ? jr[idx] : 0.f;
    unsigned long long m = __ballot(v != 0.f);
    while (m) {
      int c = c0 + __ffsll((unsigned long long)m) - 1;
      m &= m - 1;
      const float4 w = *(const float4*)(jcW + (size_t)c * NS + lane * 4);
      a0 += w.x; a1 += w.y; a2 += w.z; a3 += w.w;
    }
  }
  ushort4 o;
  o.x = bf16b(a0); o.y = bf16b(a1); o.z = bf16b(a2); o.w = bf16b(a3);
  *(ushort4*)(outp + row * NS + lane * 4) = o;
}

// ---------------- Fused tree-level GEMM + LSTM cell ----------------
// z[m][pc] = sum_k A[m][k]*Bw[k][pc],  A row m = [h[2m] | h[2m+1] | inputx[jr(m)]] (768)
// Block: 128 rows x 320 packed cols (one slice), 8 waves (4 row x 2 col), K-chunks of 32.
template <bool FIRST, bool LAST>
__global__ __launch_bounds__(512) void level_kernel(
    const unsigned short* __restrict__ h_in,  // FIRST: ln_b16 table; else (2M,256) bf16
    const float* __restrict__ c_in,           // (2M,256) f32 (unused if FIRST)
    const unsigned short* __restrict__ inpx,  // (B*15,256) bf16
    const unsigned short* __restrict__ w12sw, // packed weight images
    const float* __restrict__ bias_zp,        // (1280) packed
    unsigned short* __restrict__ h_out,       // (M,256) bf16 (if !LAST)
    float* __restrict__ c_out,                // (M,256) f32 (if !LAST)
    float* __restrict__ state_out,            // (B,256) f32 (if LAST)
    const int* __restrict__ leaf,             // leaf ids (used if FIRST)
    int log2n, int joff) {
  __shared__ __align__(1024) char ldsA[2 * 8192];
  __shared__ __align__(1024) char ldsB[2 * 20480];
  const int tid = threadIdx.x, lane = tid & 63, wv = tid >> 6;
  const int wrow = wv >> 1, wcol = wv & 1;
  const int m0 = blockIdx.x * 128;
  const int slice = blockIdx.y;
  const int n = 1 << log2n;

  f32x4 acc[2][10];
#pragma unroll
  for (int a = 0; a < 2; ++a)
#pragma unroll
    for (int t = 0; t < 10; ++t) acc[a][t] = (f32x4){0.f, 0.f, 0.f, 0.f};

  auto stageA = [&](int kc, int buf) {
    const int rl = wv * 16 + (lane >> 2);
    const int slot = lane & 3;
    const int ss = slot ^ ((rl >> 1) & 3);  // global 16B-chunk to fetch for this physical slot
    const int m = m0 + rl;
    const char* src;
    if (kc < 16) {
      if (FIRST) {
        int pair = 2 * m + (kc >> 3);
        int id = leaf[pair];
        src = (const char*)h_in + ((size_t)id * 512 + (size_t)(kc & 7) * 64 + ss * 16);
      } else {
        src = (const char*)h_in + ((size_t)m * 1024 + (size_t)kc * 64 + ss * 16);
      }
    } else {
      int b = m >> log2n, i = m & (n - 1);
      size_t jr = (size_t)b * 15 + joff + i;
      src = (const char*)inpx + (jr * 512 + (size_t)(kc - 16) * 64 + ss * 16);
    }
    char* dst = ldsA + buf * 8192 + wv * 1024;  // wave-uniform; HW adds lane*16
    g2l16(src, dst);
  };
  auto stageB = [&](int kc, int buf) {
    const char* base = (const char*)w12sw + (size_t)(slice * 24 + kc) * 20480;
    char* db = ldsB + buf * 20480;
    for (int i = wv; i < 20; i += 8)
      g2l16(base + i * 1024 + lane * 16, db + i * 1024);
  };

  stageA(0, 0);
  stageB(0, 0);
  __syncthreads();
  for (int kc = 0; kc < 24; ++kc) {
    int cur = kc & 1;
    if (kc < 23) { stageA(kc + 1, cur ^ 1); stageB(kc + 1, cur ^ 1); }
    const char* pA = ldsA + cur * 8192;
    const char* pB = ldsB + cur * 20480;
    const int s = lane >> 4;
    const int r0 = wrow * 32 + (lane & 15);
    const int r1 = r0 + 16;
    bf16x8 a0 = *(const bf16x8*)(pA + r0 * 64 + ((s ^ ((r0 >> 1) & 3)) << 4));
    bf16x8 a1 = *(const bf16x8*)(pA + r1 * 64 + ((s ^ ((r1 >> 1) & 3)) << 4));
#pragma unroll
    for (int t = 0; t < 10; ++t) {
      int nc = wcol * 160 + t * 16 + (lane & 15);
      bf16x8 bb = *(const bf16x8*)(pB + nc * 64 + ((s ^ ((nc >> 1) & 3)) << 4));
      acc[0][t] = __builtin_amdgcn_mfma_f32_16x16x32_bf16(a0, bb, acc[0][t], 0, 0, 0);
      acc[1][t] = __builtin_amdgcn_mfma_f32_16x16x32_bf16(a1, bb, acc[1][t], 0, 0, 0);
    }
    __syncthreads();
  }

  // Epilogue: lane-local LSTM cell. acc[rt][g*2+h2][r] -> gate g, unit h2-block.
  float bias[5][2];
#pragma unroll
  for (int g = 0; g < 5; ++g)
#pragma unroll
    for (int h2 = 0; h2 < 2; ++h2)
      bias[g][h2] = bias_zp[slice * 320 + wcol * 160 + (g * 2 + h2) * 16 + (lane & 15)];

#pragma unroll
  for (int rt = 0; rt < 2; ++rt) {
#pragma unroll
    for (int r = 0; r < 4; ++r) {
      int row = m0 + wrow * 32 + rt * 16 + (lane >> 4) * 4 + r;
#pragma unroll
      for (int h2 = 0; h2 < 2; ++h2) {
        int u = slice * 64 + wcol * 32 + h2 * 16 + (lane & 15);
        float za = acc[rt][0 + h2][r] + bias[0][h2];
        float zi = acc[rt][2 + h2][r] + bias[1][h2];
        float zo = acc[rt][8 + h2][r] + bias[4][h2];
        float cnew = tanhfast(za) * sigf(zi);
        if (!FIRST) {
          float zf1 = acc[rt][4 + h2][r] + bias[2][h2];
          float zf2 = acc[rt][6 + h2][r] + bias[3][h2];
          float cl = c_in[(size_t)(2 * row) * NS + u];
          float cr = c_in[(size_t)(2 * row + 1) * NS + u];
          cnew += sigf(zf1) * cl + sigf(zf2) * cr;
        }
        float hnew = sigf(zo) * tanhfast(cnew);
        if (LAST) {
          state_out[(size_t)row * NS + u] = hnew;
        } else {
          h_out[(size_t)row * NS + u] = bf16b(hnew);
          c_out[(size_t)row * NS + u] = cnew;
        }
      }
    }
  }
}

// ---------------- Final head: relu([state|action] @ fc_W + fc_b) @ out_W + out_b ----------------
__global__ __launch_bounds__(256) void fc_kernel(
    const float* __restrict__ state, const float* __restrict__ ln_f32,
    const int* __restrict__ action_ids, const float* __restrict__ fcW,
    const float* __restrict__ fcb, const float* __restrict__ outW,
    const float* __restrict__ outb, float* __restrict__ out) {
  __shared__ float xt[32][512];
  const int tid = threadIdx.x, lane = tid & 63, wv = tid >> 6;
  const int m0 = blockIdx.x * 32;
  for (int idx = tid; idx < 32 * 256; idx += 256) {
    int r = idx >> 8, c = idx & 255;
    xt[r][c] = state[(size_t)(m0 + r) * NS + c];
    xt[r][256 + c] = ln_f32[(size_t)action_ids[m0 + r] * NS + c];
  }
  __syncthreads();
  float y[8][4];
#pragma unroll
  for (int r = 0; r < 8; ++r)
#pragma unroll
    for (int j = 0; j < 4; ++j) y[r][j] = 0.f;
  const int rbase = wv * 8;
  for (int k = 0; k < 512; ++k) {
    float4 w = *(const float4*)(fcW + (size_t)k * NS + lane * 4);
#pragma unroll
    for (int r = 0; r < 8; ++r) {
      float xv = xt[rbase + r][k];
      y[r][0] += xv * w.x; y[r][1] += xv * w.y;
      y[r][2] += xv * w.z; y[r][3] += xv * w.w;
    }
  }
  float4 ow = *(const float4*)(outW + lane * 4);
  float4 fb = *(const float4*)(fcb + lane * 4);
#pragma unroll
  for (int r = 0; r < 8; ++r) {
    float p = fmaxf(y[r][0] + fb.x, 0.f) * ow.x + fmaxf(y[r][1] + fb.y, 0.f) * ow.y +
              fmaxf(y[r][2] + fb.z, 0.f) * ow.z + fmaxf(y[r][3] + fb.w, 0.f) * ow.w;
    for (int o = 1; o < 64; o <<= 1) p += __shfl_xor(p, o);
    if (lane == 0) out[m0 + rbase + r] = p + outb[0];
  }
}

extern "C" void kernel_launch(void* const* d_in, const int* in_sizes, int n_in,
                              void* d_out, int out_size, void* d_ws, size_t ws_size,
                              hipStream_t stream) {
  const int* leaf_ids = (const int*)d_in[0];
  const int* action_ids = (const int*)d_in[1];
  const float* join_cols = (const float*)d_in[2];
  const float* emb = (const float*)d_in[3];
  const float* ln_g = (const float*)d_in[4];
  const float* ln_b = (const float*)d_in[5];
  const float* jc_W = (const float*)d_in[6];
  const float* jc_b = (const float*)d_in[7];
  const float* W1 = (const float*)d_in[8];
  const float* b1 = (const float*)d_in[9];
  const float* W2 = (const float*)d_in[10];
  const float* b2 = (const float*)d_in[11];
  const float* W0 = (const float*)d_in[12];
  const float* b0 = (const float*)d_in[13];
  const float* fc_W = (const float*)d_in[14];
  const float* fc_b = (const float*)d_in[15];
  const float* out_W = (const float*)d_in[16];
  const float* out_b = (const float*)d_in[17];

  char* ws = (char*)d_ws;
  size_t o = 0;
  auto alloc = [&](size_t bytes) {
    size_t r = o;
    o += (bytes + 255) & ~(size_t)255;
    return r;
  };
  float* ln_f32 = (float*)(ws + alloc((size_t)NT * NS * 4));
  unsigned short* ln_b16 = (unsigned short*)(ws + alloc((size_t)NT * NS * 2));
  unsigned short* w12sw = (unsigned short*)(ws + alloc((size_t)4 * 24 * 20480));
  float* bias_zp = (float*)(ws + alloc((size_t)NS5 * 4));
  unsigned short* inpx = (unsigned short*)(ws + alloc((size_t)NROWS_JC * NS * 2));
  unsigned short* hX = (unsigned short*)(ws + alloc((size_t)NB * 8 * NS * 2));
  unsigned short* hY = (unsigned short*)(ws + alloc((size_t)NB * 4 * NS * 2));
  float* cX = (float*)(ws + alloc((size_t)NB * 8 * NS * 4));
  float* cY = (float*)(ws + alloc((size_t)NB * 4 * NS * 4));
  float* state = (float*)(ws + alloc((size_t)NB * NS * 4));
  (void)ws_size; (void)in_sizes; (void)n_in; (void)out_size;

  ln_kernel<<<NT, 256, 0, stream>>>(emb, ln_g, ln_b, ln_f32, ln_b16);
  pack_w12<<<3840, 256, 0, stream>>>(W1, W2, W0, w12sw);
  bias_kernel<<<5, 256, 0, stream>>>(b1, b2, b0, jc_b, W0, bias_zp);
  inputx_kernel<<<NROWS_JC / 4, 256, 0, stream>>>(join_cols, jc_W, inpx);

  // Level 0: n=8, off=0, M=65536
  level_kernel<true, false><<<dim3(512, 4), 512, 0, stream>>>(
      ln_b16, nullptr, inpx, w12sw, bias_zp, hX, cX, nullptr, leaf_ids, 3, 0);
  // Level 1: n=4, off=8, M=32768
  level_kernel<false, false><<<dim3(256, 4), 512, 0, stream>>>(
      hX, cX, inpx, w12sw, bias_zp, hY, cY, nullptr, leaf_ids, 2, 8);
  // Level 2: n=2, off=12, M=16384
  level_kernel<false, false><<<dim3(128, 4), 512, 0, stream>>>(
      hY, cY, inpx, w12sw, bias_zp, hX, cX, nullptr, leaf_ids, 1, 12);
  // Level 3: n=1, off=14, M=8192 -> state (f32)
  level_kernel<false, true><<<dim3(64, 4), 512, 0, stream>>>(
      hX, cX, inpx, w12sw, bias_zp, nullptr, nullptr, state, leaf_ids, 0, 14);

  fc_kernel<<<NB / 32, 256, 0, stream>>>(state, ln_f32, action_ids, fc_W, fc_b,
                                         out_W, out_b, (float*)d_out);
}

// Round 2
// 542.810 us; speedup vs baseline: 1.0129x; 1.0129x over previous
//
#include <hip/hip_runtime.h>
#include <hip/hip_bf16.h>
#include <stdint.h>

// Problem constants
#define NB 8192     // B
#define NL 16       // L
#define NS 256      // S
#define NT 1000     // T
#define NC 500      // C
#define NS5 1280    // 5*S
#define NROWS_JC (NB*15)   // 122880 join rows / inputx rows

typedef __attribute__((ext_vector_type(8))) short bf16x8;
typedef __attribute__((ext_vector_type(4))) float f32x4;

typedef __attribute__((address_space(1))) const void gas_void;
typedef __attribute__((address_space(3))) void las_void;

__device__ __forceinline__ void g2l16(const void* g, void* l) {
  __builtin_amdgcn_global_load_lds((gas_void*)g, (las_void*)l, 16, 0, 0);
}

__device__ __forceinline__ float sigf(float x) { return 1.f / (1.f + __expf(-x)); }
__device__ __forceinline__ float tanhfast(float x) {
  float e = __expf(2.f * fabsf(x));
  float t = 1.f - 2.f / (e + 1.f);
  return copysignf(t, x);
}
__device__ __forceinline__ unsigned short bf16b(float x) {
  __hip_bfloat16 h = __float2bfloat16(x);
  return *reinterpret_cast<unsigned short*>(&h);
}

// Gate-interleaved packed-column decode (quarter-based so each col-wave is
// gate-complete for 16 units).
// packed col pc = slice*320 + q*80 + g*16 + u16
//   -> unit U = slice*64 + q*16 + u16, gate g, orig col = g*256 + U
__device__ __forceinline__ int origcol(int slice, int nc) {
  int q = nc / 80, rem = nc % 80;
  int g = rem / 16, u16 = rem % 16;
  int U = slice * 64 + q * 16 + u16;
  return g * 256 + U;
}

// ---------------- LayerNorm of the embedding table ----------------
__global__ __launch_bounds__(256) void ln_kernel(
    const float* __restrict__ emb, const float* __restrict__ g,
    const float* __restrict__ b, float* __restrict__ of32,
    unsigned short* __restrict__ ob16) {
  int t = blockIdx.x;
  int i = threadIdx.x;
  int lane = i & 63, wv = i >> 6;
  float x = emb[t * NS + i];
  float s = x, s2 = x * x;
  for (int o = 1; o < 64; o <<= 1) {
    s += __shfl_xor(s, o);
    s2 += __shfl_xor(s2, o);
  }
  __shared__ float rs[4], rs2[4];
  if (lane == 0) { rs[wv] = s; rs2[wv] = s2; }
  __syncthreads();
  float S = rs[0] + rs[1] + rs[2] + rs[3];
  float S2 = rs2[0] + rs2[1] + rs2[2] + rs2[3];
  float mu = S * (1.f / NS);
  float var = S2 * (1.f / NS) - mu * mu;
  float y = (x - mu) * rsqrtf(var + 1e-5f) * g[i] + b[i];
  of32[t * NS + i] = y;
  ob16[t * NS + i] = bf16b(y);
}

// ---------------- Pack [W1;W2;W0] into per-K-chunk images (L2-resident B) ----------------
// image: [slice(4)][kc(24)][20480 bytes]; within chunk: value (nc, k=kc*32+kg*8+j)
// at byte nc*64 + kg*16 + j*2.  One thread builds one 16B slot (coalesced write).
__global__ __launch_bounds__(256) void pack_w12(
    const float* __restrict__ W1, const float* __restrict__ W2,
    const float* __restrict__ W0, unsigned short* __restrict__ out) {
  int e = blockIdx.x * 256 + threadIdx.x;  // 4*24*320*4 = 122880 slots
  if (e >= 4 * 24 * 320 * 4) return;
  int kg = e & 3;
  int r = e >> 2;
  int nc = r % 320; r /= 320;
  int kc = r % 24;
  int slice = r / 24;
  int oc = origcol(slice, nc);
  int kbase = kc * 32 + kg * 8;
  ushort4 v0, v1;
  unsigned short tmp[8];
#pragma unroll
  for (int j = 0; j < 8; ++j) {
    int k = kbase + j;
    float x;
    if (k < 256) x = W1[(size_t)k * NS5 + oc];
    else if (k < 512) x = W2[(size_t)(k - 256) * NS5 + oc];
    else x = W0[(size_t)(k - 512) * NS5 + oc];
    tmp[j] = bf16b(x);
  }
  v0 = make_ushort4(tmp[0], tmp[1], tmp[2], tmp[3]);
  v1 = make_ushort4(tmp[4], tmp[5], tmp[6], tmp[7]);
  size_t dst = (size_t)(slice * 24 + kc) * 20480 + (size_t)nc * 64 + kg * 16;
  *(ushort4*)((char*)out + dst) = v0;
  *(ushort4*)((char*)out + dst + 8) = v1;
}

// ---------------- Combined z-bias (b1+b2+b0), packed columns ----------------
// (jc_b is folded into inputx rows, so its W0 product is handled by the GEMM.)
__global__ __launch_bounds__(256) void bias_kernel(
    const float* __restrict__ b1, const float* __restrict__ b2,
    const float* __restrict__ b0, float* __restrict__ bias_zp) {
  int pc = blockIdx.x * 256 + threadIdx.x;
  if (pc >= NS5) return;
  int slice = pc / 320, nc = pc % 320;
  int oc = origcol(slice, nc);
  bias_zp[pc] = b1[oc] + b2[oc] + b0[oc];
}

// ---------------- Sparse join: inputx = join_cols @ jc_W + jc_b ----------------
__global__ __launch_bounds__(256) void inputx_kernel(
    const float* __restrict__ jc, const float* __restrict__ jcW,
    const float* __restrict__ jcb, unsigned short* __restrict__ outp) {
  int wv = threadIdx.x >> 6, lane = threadIdx.x & 63;
  size_t row = (size_t)blockIdx.x * 4 + wv;  // < 122880
  const float* jr = jc + row * NC;
  const float4 jb = *(const float4*)(jcb + lane * 4);
  float a0 = jb.x, a1 = jb.y, a2 = jb.z, a3 = jb.w;
  for (int c0 = 0; c0 < NC; c0 += 64) {
    int idx = c0 + lane;
    float v = (idx < NC) ? jr[idx] : 0.f;
    unsigned long long m = __ballot(v != 0.f);
    while (m) {
      int c = c0 + __ffsll((unsigned long long)m) - 1;
      m &= m - 1;
      const float4 w = *(const float4*)(jcW + (size_t)c * NS + lane * 4);
      a0 += w.x; a1 += w.y; a2 += w.z; a3 += w.w;
    }
  }
  ushort4 o;
  o.x = bf16b(a0); o.y = bf16b(a1); o.z = bf16b(a2); o.w = bf16b(a3);
  *(ushort4*)(outp + row * NS + lane * 4) = o;
}

// ---------------- Fused tree-level GEMM + LSTM cell ----------------
// z[m][pc] = sum_k A[m][k]*Bw[k][pc],  A row m = [h[2m] | h[2m+1] | inputx[jr(m)]] (768)
// Block: 128 rows x 320 packed cols (one slice), 8 waves as 2 row-groups x 4
// col-groups; wave tile = 64 rows x 80 cols (gate-complete, 16 units).
// A staged in LDS (double-buffered, XOR-swizzled); B read directly from the
// packed L2-resident image as contiguous 1KB wave loads.
template <bool FIRST, bool LAST>
__global__ __launch_bounds__(512, 4) void level_kernel(
    const unsigned short* __restrict__ h_in,  // FIRST: ln_b16 table; else (2M,256) bf16
    const float* __restrict__ c_in,           // (2M,256) f32 (unused if FIRST)
    const unsigned short* __restrict__ inpx,  // (B*15,256) bf16
    const unsigned short* __restrict__ w12p,  // packed weight images
    const float* __restrict__ bias_zp,        // (1280) packed
    unsigned short* __restrict__ h_out,       // (M,256) bf16 (if !LAST)
    float* __restrict__ c_out,                // (M,256) f32 (if !LAST)
    float* __restrict__ state_out,            // (B,256) f32 (if LAST)
    const int* __restrict__ leaf,             // leaf ids (used if FIRST)
    int log2n, int joff) {
  __shared__ __align__(1024) char ldsA[2 * 8192];
  const int tid = threadIdx.x, lane = tid & 63, wv = tid >> 6;
  const int wrow = wv >> 2, wcol = wv & 3;
  const int m0 = blockIdx.x * 128;
  const int slice = blockIdx.y;
  const int n = 1 << log2n;

  f32x4 acc[4][5];
#pragma unroll
  for (int a = 0; a < 4; ++a)
#pragma unroll
    for (int t = 0; t < 5; ++t) acc[a][t] = (f32x4){0.f, 0.f, 0.f, 0.f};

  // ---- staging source bases (kc-invariant per thread) ----
  const int rl = wv * 16 + (lane >> 2);                // row in tile this lane stages
  const int ss = (lane & 3) ^ ((rl >> 1) & 3);         // pre-swizzled 16B chunk
  const int m = m0 + rl;
  const char* hsrc0;
  const char* hsrc1;
  if (FIRST) {
    hsrc0 = (const char*)h_in + ((size_t)leaf[2 * m] * 512 + (size_t)ss * 16);
    hsrc1 = (const char*)h_in + ((size_t)leaf[2 * m + 1] * 512 + (size_t)ss * 16);
  } else {
    hsrc0 = (const char*)h_in + ((size_t)m * 1024 + (size_t)ss * 16);
    hsrc1 = hsrc0;
  }
  const int b_ = m >> log2n, i_ = m & (n - 1);
  const char* xsrc =
      (const char*)inpx + (((size_t)b_ * 15 + joff + i_) * 512 + (size_t)ss * 16);
  char* adst = ldsA + wv * 1024;  // wave-uniform base; HW appends lane*16

  auto stageA = [&](int kc, int buf) {
    const char* src;
    if (FIRST) {
      src = (kc < 8) ? hsrc0 + kc * 64
          : (kc < 16) ? hsrc1 + (kc - 8) * 64
                      : xsrc + (kc - 16) * 64;
    } else {
      src = (kc < 16) ? hsrc0 + kc * 64 : xsrc + (kc - 16) * 64;
    }
    g2l16(src, adst + buf * 8192);
  };

  // ---- LDS A-read offset (swizzle invariant under +16 rows => rt*1024 imm) ----
  const int ar = wrow * 64 + (lane & 15);
  const int aoff = ar * 64 + (((lane >> 4) ^ ((ar >> 1) & 3)) << 4);
  // ---- B global base: contiguous 1KB per wave-fragment ----
  const char* gB = (const char*)w12p + (size_t)slice * 24 * 20480 +
                   (size_t)(wcol * 80 + (lane & 15)) * 64 + (size_t)(lane >> 4) * 16;

  stageA(0, 0);
  __syncthreads();
  for (int kc = 0; kc < 24; ++kc) {
    const int cur = kc & 1;
    // B fragments for this kc straight from L2 (issue all 5 together)
    const char* gk = gB + (size_t)kc * 20480;
    bf16x8 bb[5];
#pragma unroll
    for (int g = 0; g < 5; ++g) bb[g] = *(const bf16x8*)(gk + g * 1024);
    if (kc < 23) stageA(kc + 1, cur ^ 1);
    const char* pA = ldsA + cur * 8192 + aoff;
    bf16x8 a0 = *(const bf16x8*)(pA);
    bf16x8 a1 = *(const bf16x8*)(pA + 1024);
    bf16x8 a2 = *(const bf16x8*)(pA + 2048);
    bf16x8 a3 = *(const bf16x8*)(pA + 3072);
#pragma unroll
    for (int g = 0; g < 5; ++g) {
      acc[0][g] = __builtin_amdgcn_mfma_f32_16x16x32_bf16(a0, bb[g], acc[0][g], 0, 0, 0);
      acc[1][g] = __builtin_amdgcn_mfma_f32_16x16x32_bf16(a1, bb[g], acc[1][g], 0, 0, 0);
      acc[2][g] = __builtin_amdgcn_mfma_f32_16x16x32_bf16(a2, bb[g], acc[2][g], 0, 0, 0);
      acc[3][g] = __builtin_amdgcn_mfma_f32_16x16x32_bf16(a3, bb[g], acc[3][g], 0, 0, 0);
    }
    __syncthreads();
  }

  // ---- Epilogue: lane-local LSTM cell ----
  float bias[5];
#pragma unroll
  for (int g = 0; g < 5; ++g)
    bias[g] = bias_zp[slice * 320 + wcol * 80 + g * 16 + (lane & 15)];
  const int u = slice * 64 + wcol * 16 + (lane & 15);

#pragma unroll
  for (int rt = 0; rt < 4; ++rt) {
#pragma unroll
    for (int r = 0; r < 4; ++r) {
      int row = m0 + wrow * 64 + rt * 16 + (lane >> 4) * 4 + r;
      float za = acc[rt][0][r] + bias[0];
      float zi = acc[rt][1][r] + bias[1];
      float zo = acc[rt][4][r] + bias[4];
      float cnew = tanhfast(za) * sigf(zi);
      if (!FIRST) {
        float zf1 = acc[rt][2][r] + bias[2];
        float zf2 = acc[rt][3][r] + bias[3];
        float cl = c_in[(size_t)(2 * row) * NS + u];
        float cr = c_in[(size_t)(2 * row + 1) * NS + u];
        cnew += sigf(zf1) * cl + sigf(zf2) * cr;
      }
      float hnew = sigf(zo) * tanhfast(cnew);
      if (LAST) {
        state_out[(size_t)row * NS + u] = hnew;
      } else {
        h_out[(size_t)row * NS + u] = bf16b(hnew);
        c_out[(size_t)row * NS + u] = cnew;
      }
    }
  }
}

// ---------------- Final head: relu([state|action] @ fc_W + fc_b) @ out_W + out_b ----------------
__global__ __launch_bounds__(256) void fc_kernel(
    const float* __restrict__ state, const float* __restrict__ ln_f32,
    const int* __restrict__ action_ids, const float* __restrict__ fcW,
    const float* __restrict__ fcb, const float* __restrict__ outW,
    const float* __restrict__ outb, float* __restrict__ out) {
  __shared__ float xt[32][512];
  const int tid = threadIdx.x, lane = tid & 63, wv = tid >> 6;
  const int m0 = blockIdx.x * 32;
  for (int idx = tid; idx < 32 * 256; idx += 256) {
    int r = idx >> 8, c = idx & 255;
    xt[r][c] = state[(size_t)(m0 + r) * NS + c];
    xt[r][256 + c] = ln_f32[(size_t)action_ids[m0 + r] * NS + c];
  }
  __syncthreads();
  float y[8][4];
#pragma unroll
  for (int r = 0; r < 8; ++r)
#pragma unroll
    for (int j = 0; j < 4; ++j) y[r][j] = 0.f;
  const int rbase = wv * 8;
  for (int k = 0; k < 512; ++k) {
    float4 w = *(const float4*)(fcW + (size_t)k * NS + lane * 4);
#pragma unroll
    for (int r = 0; r < 8; ++r) {
      float xv = xt[rbase + r][k];
      y[r][0] += xv * w.x; y[r][1] += xv * w.y;
      y[r][2] += xv * w.z; y[r][3] += xv * w.w;
    }
  }
  float4 ow = *(const float4*)(outW + lane * 4);
  float4 fb = *(const float4*)(fcb + lane * 4);
#pragma unroll
  for (int r = 0; r < 8; ++r) {
    float p = fmaxf(y[r][0] + fb.x, 0.f) * ow.x + fmaxf(y[r][1] + fb.y, 0.f) * ow.y +
              fmaxf(y[r][2] + fb.z, 0.f) * ow.z + fmaxf(y[r][3] + fb.w, 0.f) * ow.w;
    for (int o = 1; o < 64; o <<= 1) p += __shfl_xor(p, o);
    if (lane == 0) out[m0 + rbase + r] = p + outb[0];
  }
}

extern "C" void kernel_launch(void* const* d_in, const int* in_sizes, int n_in,
                              void* d_out, int out_size, void* d_ws, size_t ws_size,
                              hipStream_t stream) {
  const int* leaf_ids = (const int*)d_in[0];
  const int* action_ids = (const int*)d_in[1];
  const float* join_cols = (const float*)d_in[2];
  const float* emb = (const float*)d_in[3];
  const float* ln_g = (const float*)d_in[4];
  const float* ln_b = (const float*)d_in[5];
  const float* jc_W = (const float*)d_in[6];
  const float* jc_b = (const float*)d_in[7];
  const float* W1 = (const float*)d_in[8];
  const float* b1 = (const float*)d_in[9];
  const float* W2 = (const float*)d_in[10];
  const float* b2 = (const float*)d_in[11];
  const float* W0 = (const float*)d_in[12];
  const float* b0 = (const float*)d_in[13];
  const float* fc_W = (const float*)d_in[14];
  const float* fc_b = (const float*)d_in[15];
  const float* out_W = (const float*)d_in[16];
  const float* out_b = (const float*)d_in[17];

  char* ws = (char*)d_ws;
  size_t o = 0;
  auto alloc = [&](size_t bytes) {
    size_t r = o;
    o += (bytes + 255) & ~(size_t)255;
    return r;
  };
  float* ln_f32 = (float*)(ws + alloc((size_t)NT * NS * 4));
  unsigned short* ln_b16 = (unsigned short*)(ws + alloc((size_t)NT * NS * 2));
  unsigned short* w12p = (unsigned short*)(ws + alloc((size_t)4 * 24 * 20480));
  float* bias_zp = (float*)(ws + alloc((size_t)NS5 * 4));
  unsigned short* inpx = (unsigned short*)(ws + alloc((size_t)NROWS_JC * NS * 2));
  unsigned short* hX = (unsigned short*)(ws + alloc((size_t)NB * 8 * NS * 2));
  unsigned short* hY = (unsigned short*)(ws + alloc((size_t)NB * 4 * NS * 2));
  float* cX = (float*)(ws + alloc((size_t)NB * 8 * NS * 4));
  float* cY = (float*)(ws + alloc((size_t)NB * 4 * NS * 4));
  float* state = (float*)(ws + alloc((size_t)NB * NS * 4));
  (void)ws_size; (void)in_sizes; (void)n_in; (void)out_size;

  ln_kernel<<<NT, 256, 0, stream>>>(emb, ln_g, ln_b, ln_f32, ln_b16);
  pack_w12<<<480, 256, 0, stream>>>(W1, W2, W0, w12p);
  bias_kernel<<<5, 256, 0, stream>>>(b1, b2, b0, bias_zp);
  inputx_kernel<<<NROWS_JC / 4, 256, 0, stream>>>(join_cols, jc_W, jc_b, inpx);

  // Level 0: n=8, off=0, M=65536
  level_kernel<true, false><<<dim3(512, 4), 512, 0, stream>>>(
      ln_b16, nullptr, inpx, w12p, bias_zp, hX, cX, nullptr, leaf_ids, 3, 0);
  // Level 1: n=4, off=8, M=32768
  level_kernel<false, false><<<dim3(256, 4), 512, 0, stream>>>(
      hX, cX, inpx, w12p, bias_zp, hY, cY, nullptr, leaf_ids, 2, 8);
  // Level 2: n=2, off=12, M=16384
  level_kernel<false, false><<<dim3(128, 4), 512, 0, stream>>>(
      hY, cY, inpx, w12p, bias_zp, hX, cX, nullptr, leaf_ids, 1, 12);
  // Level 3: n=1, off=14, M=8192 -> state (f32)
  level_kernel<false, true><<<dim3(64, 4), 512, 0, stream>>>(
      hX, cX, inpx, w12p, bias_zp, nullptr, nullptr, state, leaf_ids, 0, 14);

  fc_kernel<<<NB / 32, 256, 0, stream>>>(state, ln_f32, action_ids, fc_W, fc_b,
                                         out_W, out_b, (float*)d_out);
}

// Round 3
// 536.717 us; speedup vs baseline: 1.0244x; 1.0114x over previous
//
#include <hip/hip_runtime.h>
#include <hip/hip_bf16.h>
#include <stdint.h>

// Problem constants
#define NB 8192     // B
#define NL 16       // L
#define NS 256      // S
#define NT 1000     // T
#define NC 500      // C
#define NS5 1280    // 5*S
#define NROWS_JC (NB*15)   // 122880 join rows / inputx rows

typedef __attribute__((ext_vector_type(8))) short bf16x8;
typedef __attribute__((ext_vector_type(4))) float f32x4;

typedef __attribute__((address_space(1))) const void gas_void;
typedef __attribute__((address_space(3))) void las_void;

__device__ __forceinline__ void g2l16(const void* g, void* l) {
  __builtin_amdgcn_global_load_lds((gas_void*)g, (las_void*)l, 16, 0, 0);
}

__device__ __forceinline__ float sigf(float x) { return 1.f / (1.f + __expf(-x)); }
__device__ __forceinline__ float tanhfast(float x) {
  float e = __expf(2.f * fabsf(x));
  float t = 1.f - 2.f / (e + 1.f);
  return copysignf(t, x);
}
__device__ __forceinline__ unsigned short bf16b(float x) {
  __hip_bfloat16 h = __float2bfloat16(x);
  return *reinterpret_cast<unsigned short*>(&h);
}

// Gate-interleaved packed-column decode (quarter-based so each col-wave is
// gate-complete for 16 units).
// packed col pc = slice*320 + q*80 + g*16 + u16
//   -> unit U = slice*64 + q*16 + u16, gate g, orig col = g*256 + U
__device__ __forceinline__ int origcol(int slice, int nc) {
  int q = nc / 80, rem = nc % 80;
  int g = rem / 16, u16 = rem % 16;
  int U = slice * 64 + q * 16 + u16;
  return g * 256 + U;
}

// ---------------- LayerNorm of the embedding table ----------------
__global__ __launch_bounds__(256) void ln_kernel(
    const float* __restrict__ emb, const float* __restrict__ g,
    const float* __restrict__ b, float* __restrict__ of32,
    unsigned short* __restrict__ ob16) {
  int t = blockIdx.x;
  int i = threadIdx.x;
  int lane = i & 63, wv = i >> 6;
  float x = emb[t * NS + i];
  float s = x, s2 = x * x;
  for (int o = 1; o < 64; o <<= 1) {
    s += __shfl_xor(s, o);
    s2 += __shfl_xor(s2, o);
  }
  __shared__ float rs[4], rs2[4];
  if (lane == 0) { rs[wv] = s; rs2[wv] = s2; }
  __syncthreads();
  float S = rs[0] + rs[1] + rs[2] + rs[3];
  float S2 = rs2[0] + rs2[1] + rs2[2] + rs2[3];
  float mu = S * (1.f / NS);
  float var = S2 * (1.f / NS) - mu * mu;
  float y = (x - mu) * rsqrtf(var + 1e-5f) * g[i] + b[i];
  of32[t * NS + i] = y;
  ob16[t * NS + i] = bf16b(y);
}

// ---------------- Pack [W1;W2;W0] into per-K-chunk images (L2-resident B) ----------------
// image: [slice(4)][kc(24)][20480 bytes]; within chunk: value (nc, k=kc*32+kg*8+j)
// at byte nc*64 + kg*16 + j*2.  One thread builds one 16B slot (coalesced write).
__global__ __launch_bounds__(256) void pack_w12(
    const float* __restrict__ W1, const float* __restrict__ W2,
    const float* __restrict__ W0, unsigned short* __restrict__ out) {
  int e = blockIdx.x * 256 + threadIdx.x;  // 4*24*320*4 = 122880 slots
  if (e >= 4 * 24 * 320 * 4) return;
  int kg = e & 3;
  int r = e >> 2;
  int nc = r % 320; r /= 320;
  int kc = r % 24;
  int slice = r / 24;
  int oc = origcol(slice, nc);
  int kbase = kc * 32 + kg * 8;
  ushort4 v0, v1;
  unsigned short tmp[8];
#pragma unroll
  for (int j = 0; j < 8; ++j) {
    int k = kbase + j;
    float x;
    if (k < 256) x = W1[(size_t)k * NS5 + oc];
    else if (k < 512) x = W2[(size_t)(k - 256) * NS5 + oc];
    else x = W0[(size_t)(k - 512) * NS5 + oc];
    tmp[j] = bf16b(x);
  }
  v0 = make_ushort4(tmp[0], tmp[1], tmp[2], tmp[3]);
  v1 = make_ushort4(tmp[4], tmp[5], tmp[6], tmp[7]);
  size_t dst = (size_t)(slice * 24 + kc) * 20480 + (size_t)nc * 64 + kg * 16;
  *(ushort4*)((char*)out + dst) = v0;
  *(ushort4*)((char*)out + dst + 8) = v1;
}

// ---------------- Combined z-bias (b1+b2+b0), packed columns ----------------
__global__ __launch_bounds__(256) void bias_kernel(
    const float* __restrict__ b1, const float* __restrict__ b2,
    const float* __restrict__ b0, float* __restrict__ bias_zp) {
  int pc = blockIdx.x * 256 + threadIdx.x;
  if (pc >= NS5) return;
  int slice = pc / 320, nc = pc % 320;
  int oc = origcol(slice, nc);
  bias_zp[pc] = b1[oc] + b2[oc] + b0[oc];
}

// ---------------- Sparse join: inputx = join_cols @ jc_W + jc_b ----------------
// One wave per row. Whole 500-float row loaded as 2 float4/lane issued
// together (no serialized 8-iter chain), then register-only ballots and
// ~5 gathered jcW row-adds (jcW is L2-resident, 1KB coalesced per gather).
__global__ __launch_bounds__(256) void inputx_kernel(
    const float* __restrict__ jc, const float* __restrict__ jcW,
    const float* __restrict__ jcb, unsigned short* __restrict__ outp) {
  int wv = threadIdx.x >> 6, lane = threadIdx.x & 63;
  size_t row = (size_t)blockIdx.x * 4 + wv;  // < 122880
  const float* jr = jc + row * NC;
  // row*NC*4 = row*2000 bytes, multiple of 16 -> float4-aligned.
  float4 v0 = *(const float4*)(jr + lane * 4);           // cols 0..255
  float4 v1 = make_float4(0.f, 0.f, 0.f, 0.f);           // cols 256..499
  if (lane < 61) v1 = *(const float4*)(jr + 256 + lane * 4);
  const float4 jb = *(const float4*)(jcb + lane * 4);
  float a0 = jb.x, a1 = jb.y, a2 = jb.z, a3 = jb.w;

#define GATHER_MASK(val, cbase)                                       \
  {                                                                   \
    unsigned long long m = __ballot((val) != 0.f);                    \
    while (m) {                                                       \
      int l = __ffsll(m) - 1;                                         \
      m &= m - 1;                                                     \
      int c = (cbase) + l * 4;                                        \
      const float4 w = *(const float4*)(jcW + (size_t)c * NS + lane * 4); \
      a0 += w.x; a1 += w.y; a2 += w.z; a3 += w.w;                     \
    }                                                                 \
  }
  GATHER_MASK(v0.x, 0) GATHER_MASK(v0.y, 1) GATHER_MASK(v0.z, 2) GATHER_MASK(v0.w, 3)
  GATHER_MASK(v1.x, 256) GATHER_MASK(v1.y, 257) GATHER_MASK(v1.z, 258) GATHER_MASK(v1.w, 259)
#undef GATHER_MASK

  ushort4 o;
  o.x = bf16b(a0); o.y = bf16b(a1); o.z = bf16b(a2); o.w = bf16b(a3);
  *(ushort4*)(outp + row * NS + lane * 4) = o;
}

// ---------------- Fused tree-level GEMM + LSTM cell ----------------
// z[m][pc] = sum_k A[m][k]*Bw[k][pc],  A row m = [h[2m] | h[2m+1] | inputx(m)] (768)
// Block: 128 rows x 320 packed cols (one slice), 8 waves as 2 row-groups x 4
// col-groups; wave tile = 64 rows x 80 cols (gate-complete, 16 units).
// A: triple-buffered LDS via global_load_lds, depth-2 prefetch, raw s_barrier
// + counted vmcnt(1) (never drained to 0 in the loop).  B: registers from the
// packed L2-resident image (contiguous 1KB per wave-fragment).
template <bool FIRST, bool LAST>
__global__ __launch_bounds__(512, 3) void level_kernel(
    const unsigned short* __restrict__ h_in,  // FIRST: ln_b16 table; else (2M,256) bf16
    const float* __restrict__ c_in,           // (2M,256) f32 (unused if FIRST)
    const unsigned short* __restrict__ inpx,  // (B*15,256) bf16
    const unsigned short* __restrict__ w12p,  // packed weight images
    const float* __restrict__ bias_zp,        // (1280) packed
    unsigned short* __restrict__ h_out,       // (M,256) bf16 (if !LAST)
    float* __restrict__ c_out,                // (M,256) f32 (if !LAST)
    float* __restrict__ state_out,            // (B,256) f32 (if LAST)
    const int* __restrict__ leaf,             // leaf ids (used if FIRST)
    int log2n, int joff) {
  __shared__ __align__(1024) char ldsA[3 * 8192];
  const int tid = threadIdx.x, lane = tid & 63, wv = tid >> 6;
  const int wrow = wv >> 2, wcol = wv & 3;
  const int m0 = blockIdx.x * 128;
  const int slice = blockIdx.y;
  const int n = 1 << log2n;

  f32x4 acc[4][5];
#pragma unroll
  for (int a = 0; a < 4; ++a)
#pragma unroll
    for (int t = 0; t < 5; ++t) acc[a][t] = (f32x4){0.f, 0.f, 0.f, 0.f};

  // ---- staging source bases (kc-invariant per thread) ----
  const int rl = wv * 16 + (lane >> 2);                // row in tile this lane stages
  const int ss = (lane & 3) ^ ((rl >> 1) & 3);         // pre-swizzled 16B chunk
  const int m = m0 + rl;
  const char* hsrc0;
  const char* hsrc1;
  if (FIRST) {
    hsrc0 = (const char*)h_in + ((size_t)leaf[2 * m] * 512 + (size_t)ss * 16);
    hsrc1 = (const char*)h_in + ((size_t)leaf[2 * m + 1] * 512 + (size_t)ss * 16);
  } else {
    hsrc0 = (const char*)h_in + ((size_t)m * 1024 + (size_t)ss * 16);
    hsrc1 = hsrc0;
  }
  const int b_ = m >> log2n, i_ = m & (n - 1);
  const char* xsrc =
      (const char*)inpx + (((size_t)b_ * 15 + joff + i_) * 512 + (size_t)ss * 16);
  char* adst = ldsA + wv * 1024;  // wave-uniform base; HW appends lane*16

  auto stageA = [&](int kc, int buf) {
    const char* src;
    if (FIRST) {
      src = (kc < 8) ? hsrc0 + kc * 64
          : (kc < 16) ? hsrc1 + (kc - 8) * 64
                      : xsrc + (kc - 16) * 64;
    } else {
      src = (kc < 16) ? hsrc0 + kc * 64 : xsrc + (kc - 16) * 64;
    }
    g2l16(src, adst + buf * 8192);
  };

  // ---- LDS A-read offset (swizzle invariant under +16 rows => rt*1024 imm) ----
  const int ar = wrow * 64 + (lane & 15);
  const int aoff = ar * 64 + (((lane >> 4) ^ ((ar >> 1) & 3)) << 4);
  // ---- B global base: contiguous 1KB per wave-fragment ----
  const char* gB = (const char*)w12p + (size_t)slice * 24 * 20480 +
                   (size_t)(wcol * 80 + (lane & 15)) * 64 + (size_t)(lane >> 4) * 16;

  // Prologue: stage A(0), A(1); confirm own A(0) landed before first barrier.
  stageA(0, 0);
  stageA(1, 1);
  asm volatile("s_waitcnt vmcnt(1)" ::: "memory");

  int cur = 0;
  for (int kc = 0; kc < 24; ++kc) {
    // All waves finished reading buf (kc-1)%3 (its ds_reads completed before
    // their vmcnt/lgkm wait last iter), and every wave has confirmed its own
    // A(kc) DMA.  Safe to release readers of buf kc%3 and overwrite (kc+2)%3.
    __builtin_amdgcn_s_barrier();
    // B fragments for this kc straight from L2
    const char* gk = gB + (size_t)kc * 20480;
    bf16x8 bb[5];
#pragma unroll
    for (int g = 0; g < 5; ++g) bb[g] = *(const bf16x8*)(gk + g * 1024);
    // depth-2 A prefetch: newest in-flight op, allowed to stay outstanding
    if (kc < 22) stageA(kc + 2, cur == 0 ? 2 : cur - 1);  // (kc+2)%3
    const char* pA = ldsA + cur * 8192 + aoff;
    bf16x8 a0 = *(const bf16x8*)(pA);
    bf16x8 a1 = *(const bf16x8*)(pA + 1024);
    bf16x8 a2 = *(const bf16x8*)(pA + 2048);
    bf16x8 a3 = *(const bf16x8*)(pA + 3072);
    // Counted wait: everything except the newest in-flight op (the A(kc+2)
    // DMA) must be retired -> B(kc) regs ready, A(kc+1) landed for next iter.
    asm volatile("s_waitcnt vmcnt(1) lgkmcnt(0)" ::: "memory");
    __builtin_amdgcn_sched_barrier(0);
#pragma unroll
    for (int g = 0; g < 5; ++g) {
      acc[0][g] = __builtin_amdgcn_mfma_f32_16x16x32_bf16(a0, bb[g], acc[0][g], 0, 0, 0);
      acc[1][g] = __builtin_amdgcn_mfma_f32_16x16x32_bf16(a1, bb[g], acc[1][g], 0, 0, 0);
      acc[2][g] = __builtin_amdgcn_mfma_f32_16x16x32_bf16(a2, bb[g], acc[2][g], 0, 0, 0);
      acc[3][g] = __builtin_amdgcn_mfma_f32_16x16x32_bf16(a3, bb[g], acc[3][g], 0, 0, 0);
    }
    cur = (cur == 2) ? 0 : cur + 1;
  }

  // ---- Epilogue: lane-local LSTM cell ----
  float bias[5];
#pragma unroll
  for (int g = 0; g < 5; ++g)
    bias[g] = bias_zp[slice * 320 + wcol * 80 + g * 16 + (lane & 15)];
  const int u = slice * 64 + wcol * 16 + (lane & 15);

#pragma unroll
  for (int rt = 0; rt < 4; ++rt) {
#pragma unroll
    for (int r = 0; r < 4; ++r) {
      int row = m0 + wrow * 64 + rt * 16 + (lane >> 4) * 4 + r;
      float za = acc[rt][0][r] + bias[0];
      float zi = acc[rt][1][r] + bias[1];
      float zo = acc[rt][4][r] + bias[4];
      float cnew = tanhfast(za) * sigf(zi);
      if (!FIRST) {
        float zf1 = acc[rt][2][r] + bias[2];
        float zf2 = acc[rt][3][r] + bias[3];
        float cl = c_in[(size_t)(2 * row) * NS + u];
        float cr = c_in[(size_t)(2 * row + 1) * NS + u];
        cnew += sigf(zf1) * cl + sigf(zf2) * cr;
      }
      float hnew = sigf(zo) * tanhfast(cnew);
      if (LAST) {
        state_out[(size_t)row * NS + u] = hnew;
      } else {
        h_out[(size_t)row * NS + u] = bf16b(hnew);
        c_out[(size_t)row * NS + u] = cnew;
      }
    }
  }
}

// ---------------- Final head: relu([state|action] @ fc_W + fc_b) @ out_W + out_b ----------------
__global__ __launch_bounds__(256) void fc_kernel(
    const float* __restrict__ state, const float* __restrict__ ln_f32,
    const int* __restrict__ action_ids, const float* __restrict__ fcW,
    const float* __restrict__ fcb, const float* __restrict__ outW,
    const float* __restrict__ outb, float* __restrict__ out) {
  __shared__ float xt[32][512];
  const int tid = threadIdx.x, lane = tid & 63, wv = tid >> 6;
  const int m0 = blockIdx.x * 32;
  for (int idx = tid; idx < 32 * 256; idx += 256) {
    int r = idx >> 8, c = idx & 255;
    xt[r][c] = state[(size_t)(m0 + r) * NS + c];
    xt[r][256 + c] = ln_f32[(size_t)action_ids[m0 + r] * NS + c];
  }
  __syncthreads();
  float y[8][4];
#pragma unroll
  for (int r = 0; r < 8; ++r)
#pragma unroll
    for (int j = 0; j < 4; ++j) y[r][j] = 0.f;
  const int rbase = wv * 8;
  for (int k = 0; k < 512; ++k) {
    float4 w = *(const float4*)(fcW + (size_t)k * NS + lane * 4);
#pragma unroll
    for (int r = 0; r < 8; ++r) {
      float xv = xt[rbase + r][k];
      y[r][0] += xv * w.x; y[r][1] += xv * w.y;
      y[r][2] += xv * w.z; y[r][3] += xv * w.w;
    }
  }
  float4 ow = *(const float4*)(outW + lane * 4);
  float4 fb = *(const float4*)(fcb + lane * 4);
#pragma unroll
  for (int r = 0; r < 8; ++r) {
    float p = fmaxf(y[r][0] + fb.x, 0.f) * ow.x + fmaxf(y[r][1] + fb.y, 0.f) * ow.y +
              fmaxf(y[r][2] + fb.z, 0.f) * ow.z + fmaxf(y[r][3] + fb.w, 0.f) * ow.w;
    for (int o = 1; o < 64; o <<= 1) p += __shfl_xor(p, o);
    if (lane == 0) out[m0 + rbase + r] = p + outb[0];
  }
}

extern "C" void kernel_launch(void* const* d_in, const int* in_sizes, int n_in,
                              void* d_out, int out_size, void* d_ws, size_t ws_size,
                              hipStream_t stream) {
  const int* leaf_ids = (const int*)d_in[0];
  const int* action_ids = (const int*)d_in[1];
  const float* join_cols = (const float*)d_in[2];
  const float* emb = (const float*)d_in[3];
  const float* ln_g = (const float*)d_in[4];
  const float* ln_b = (const float*)d_in[5];
  const float* jc_W = (const float*)d_in[6];
  const float* jc_b = (const float*)d_in[7];
  const float* W1 = (const float*)d_in[8];
  const float* b1 = (const float*)d_in[9];
  const float* W2 = (const float*)d_in[10];
  const float* b2 = (const float*)d_in[11];
  const float* W0 = (const float*)d_in[12];
  const float* b0 = (const float*)d_in[13];
  const float* fc_W = (const float*)d_in[14];
  const float* fc_b = (const float*)d_in[15];
  const float* out_W = (const float*)d_in[16];
  const float* out_b = (const float*)d_in[17];

  char* ws = (char*)d_ws;
  size_t o = 0;
  auto alloc = [&](size_t bytes) {
    size_t r = o;
    o += (bytes + 255) & ~(size_t)255;
    return r;
  };
  float* ln_f32 = (float*)(ws + alloc((size_t)NT * NS * 4));
  unsigned short* ln_b16 = (unsigned short*)(ws + alloc((size_t)NT * NS * 2));
  unsigned short* w12p = (unsigned short*)(ws + alloc((size_t)4 * 24 * 20480));
  float* bias_zp = (float*)(ws + alloc((size_t)NS5 * 4));
  unsigned short* inpx = (unsigned short*)(ws + alloc((size_t)NROWS_JC * NS * 2));
  unsigned short* hX = (unsigned short*)(ws + alloc((size_t)NB * 8 * NS * 2));
  unsigned short* hY = (unsigned short*)(ws + alloc((size_t)NB * 4 * NS * 2));
  float* cX = (float*)(ws + alloc((size_t)NB * 8 * NS * 4));
  float* cY = (float*)(ws + alloc((size_t)NB * 4 * NS * 4));
  float* state = (float*)(ws + alloc((size_t)NB * NS * 4));
  (void)ws_size; (void)in_sizes; (void)n_in; (void)out_size;

  ln_kernel<<<NT, 256, 0, stream>>>(emb, ln_g, ln_b, ln_f32, ln_b16);
  pack_w12<<<480, 256, 0, stream>>>(W1, W2, W0, w12p);
  bias_kernel<<<5, 256, 0, stream>>>(b1, b2, b0, bias_zp);
  inputx_kernel<<<NROWS_JC / 4, 256, 0, stream>>>(join_cols, jc_W, jc_b, inpx);

  // Level 0: n=8, off=0, M=65536
  level_kernel<true, false><<<dim3(512, 4), 512, 0, stream>>>(
      ln_b16, nullptr, inpx, w12p, bias_zp, hX, cX, nullptr, leaf_ids, 3, 0);
  // Level 1: n=4, off=8, M=32768
  level_kernel<false, false><<<dim3(256, 4), 512, 0, stream>>>(
      hX, cX, inpx, w12p, bias_zp, hY, cY, nullptr, leaf_ids, 2, 8);
  // Level 2: n=2, off=12, M=16384
  level_kernel<false, false><<<dim3(128, 4), 512, 0, stream>>>(
      hY, cY, inpx, w12p, bias_zp, hX, cX, nullptr, leaf_ids, 1, 12);
  // Level 3: n=1, off=14, M=8192 -> state (f32)
  level_kernel<false, true><<<dim3(64, 4), 512, 0, stream>>>(
      hX, cX, inpx, w12p, bias_zp, nullptr, nullptr, state, leaf_ids, 0, 14);

  fc_kernel<<<NB / 32, 256, 0, stream>>>(state, ln_f32, action_ids, fc_W, fc_b,
                                         out_W, out_b, (float*)d_out);
}

// Round 4
// 513.453 us; speedup vs baseline: 1.0708x; 1.0453x over previous
//
#include <hip/hip_runtime.h>
#include <hip/hip_bf16.h>
#include <stdint.h>

// Problem constants
#define NB 8192     // B
#define NL 16       // L
#define NS 256      // S
#define NT 1000     // T
#define NC 500      // C
#define NS5 1280    // 5*S
#define NROWS_JC (NB*15)   // 122880 join rows / inputx rows

typedef __attribute__((ext_vector_type(8))) short bf16x8;
typedef __attribute__((ext_vector_type(4))) float f32x4;

typedef __attribute__((address_space(1))) const void gas_void;
typedef __attribute__((address_space(3))) void las_void;

__device__ __forceinline__ void g2l16(const void* g, void* l) {
  __builtin_amdgcn_global_load_lds((gas_void*)g, (las_void*)l, 16, 0, 0);
}

__device__ __forceinline__ float sigf(float x) { return 1.f / (1.f + __expf(-x)); }
__device__ __forceinline__ float tanhfast(float x) {
  float e = __expf(2.f * fabsf(x));
  float t = 1.f - 2.f / (e + 1.f);
  return copysignf(t, x);
}
__device__ __forceinline__ unsigned short bf16b(float x) {
  __hip_bfloat16 h = __float2bfloat16(x);
  return *reinterpret_cast<unsigned short*>(&h);
}
__device__ __forceinline__ float b2f(unsigned short v) {
  union { unsigned u; float f; } x;
  x.u = (unsigned)v << 16;
  return x.f;
}

// Gate-interleaved packed-column decode (quarter-based so each col-wave is
// gate-complete for 16 units).
// packed col pc = slice*320 + q*80 + g*16 + u16
//   -> unit U = slice*64 + q*16 + u16, gate g, orig col = g*256 + U
__device__ __forceinline__ int origcol(int slice, int nc) {
  int q = nc / 80, rem = nc % 80;
  int g = rem / 16, u16 = rem % 16;
  int U = slice * 64 + q * 16 + u16;
  return g * 256 + U;
}

// ---------------- LayerNorm of the embedding table ----------------
__global__ __launch_bounds__(256) void ln_kernel(
    const float* __restrict__ emb, const float* __restrict__ g,
    const float* __restrict__ b, float* __restrict__ of32,
    unsigned short* __restrict__ ob16) {
  int t = blockIdx.x;
  int i = threadIdx.x;
  int lane = i & 63, wv = i >> 6;
  float x = emb[t * NS + i];
  float s = x, s2 = x * x;
  for (int o = 1; o < 64; o <<= 1) {
    s += __shfl_xor(s, o);
    s2 += __shfl_xor(s2, o);
  }
  __shared__ float rs[4], rs2[4];
  if (lane == 0) { rs[wv] = s; rs2[wv] = s2; }
  __syncthreads();
  float S = rs[0] + rs[1] + rs[2] + rs[3];
  float S2 = rs2[0] + rs2[1] + rs2[2] + rs2[3];
  float mu = S * (1.f / NS);
  float var = S2 * (1.f / NS) - mu * mu;
  float y = (x - mu) * rsqrtf(var + 1e-5f) * g[i] + b[i];
  of32[t * NS + i] = y;
  ob16[t * NS + i] = bf16b(y);
}

// ---------------- Pack [W1;W2;W0] into per-K-chunk SWIZZLED images ----------------
// image: [slice(4)][kc(24)][20480 bytes]; value (nc, k=kc*32+kg*8+j) at byte
//   nc*64 + ((kg ^ ((nc>>1)&3))<<4) + j*2   (XOR swizzle for conflict-free
//   ds_read_b128 after a LINEAR global->LDS DMA of the image chunk).
__global__ __launch_bounds__(256) void pack_w12(
    const float* __restrict__ W1, const float* __restrict__ W2,
    const float* __restrict__ W0, unsigned short* __restrict__ out) {
  int e = blockIdx.x * 256 + threadIdx.x;  // 4*24*320*4 = 122880 slots
  if (e >= 4 * 24 * 320 * 4) return;
  int kg = e & 3;
  int r = e >> 2;
  int nc = r % 320; r /= 320;
  int kc = r % 24;
  int slice = r / 24;
  int oc = origcol(slice, nc);
  int kbase = kc * 32 + kg * 8;
  unsigned short tmp[8];
#pragma unroll
  for (int j = 0; j < 8; ++j) {
    int k = kbase + j;
    float x;
    if (k < 256) x = W1[(size_t)k * NS5 + oc];
    else if (k < 512) x = W2[(size_t)(k - 256) * NS5 + oc];
    else x = W0[(size_t)(k - 512) * NS5 + oc];
    tmp[j] = bf16b(x);
  }
  ushort4 v0 = make_ushort4(tmp[0], tmp[1], tmp[2], tmp[3]);
  ushort4 v1 = make_ushort4(tmp[4], tmp[5], tmp[6], tmp[7]);
  size_t dst = (size_t)(slice * 24 + kc) * 20480 + (size_t)nc * 64 +
               ((kg ^ ((nc >> 1) & 3)) << 4);
  *(ushort4*)((char*)out + dst) = v0;
  *(ushort4*)((char*)out + dst + 8) = v1;
}

// ---------------- Combined z-bias (b1+b2+b0), packed columns ----------------
__global__ __launch_bounds__(256) void bias_kernel(
    const float* __restrict__ b1, const float* __restrict__ b2,
    const float* __restrict__ b0, float* __restrict__ bias_zp) {
  int pc = blockIdx.x * 256 + threadIdx.x;
  if (pc >= NS5) return;
  int slice = pc / 320, nc = pc % 320;
  int oc = origcol(slice, nc);
  bias_zp[pc] = b1[oc] + b2[oc] + b0[oc];
}

// ---------------- Sparse join: inputx = join_cols @ jc_W + jc_b ----------------
__global__ __launch_bounds__(256) void inputx_kernel(
    const float* __restrict__ jc, const float* __restrict__ jcW,
    const float* __restrict__ jcb, unsigned short* __restrict__ outp) {
  int wv = threadIdx.x >> 6, lane = threadIdx.x & 63;
  size_t row = (size_t)blockIdx.x * 4 + wv;  // < 122880
  const float* jr = jc + row * NC;
  // row*NC*4 = row*2000 bytes, multiple of 16 -> float4-aligned.
  float4 v0 = *(const float4*)(jr + lane * 4);           // cols 0..255
  float4 v1 = make_float4(0.f, 0.f, 0.f, 0.f);           // cols 256..499
  if (lane < 61) v1 = *(const float4*)(jr + 256 + lane * 4);
  const float4 jb = *(const float4*)(jcb + lane * 4);
  float a0 = jb.x, a1 = jb.y, a2 = jb.z, a3 = jb.w;

#define GATHER_MASK(val, cbase)                                       \
  {                                                                   \
    unsigned long long m = __ballot((val) != 0.f);                    \
    while (m) {                                                       \
      int l = __ffsll(m) - 1;                                         \
      m &= m - 1;                                                     \
      int c = (cbase) + l * 4;                                        \
      const float4 w = *(const float4*)(jcW + (size_t)c * NS + lane * 4); \
      a0 += w.x; a1 += w.y; a2 += w.z; a3 += w.w;                     \
    }                                                                 \
  }
  GATHER_MASK(v0.x, 0) GATHER_MASK(v0.y, 1) GATHER_MASK(v0.z, 2) GATHER_MASK(v0.w, 3)
  GATHER_MASK(v1.x, 256) GATHER_MASK(v1.y, 257) GATHER_MASK(v1.z, 258) GATHER_MASK(v1.w, 259)
#undef GATHER_MASK

  ushort4 o;
  o.x = bf16b(a0); o.y = bf16b(a1); o.z = bf16b(a2); o.w = bf16b(a3);
  *(ushort4*)(outp + row * NS + lane * 4) = o;
}

// ---------------- Fused tree-level GEMM + LSTM cell ----------------
// z[m][pc] = sum_k A[m][k]*Bw[k][pc],  A row m = [h[2m] | h[2m+1] | inputx(m)] (768)
// Block: 128 rows x 320 packed cols (one slice), 8 waves as 2 row-groups x 4
// col-groups; wave tile = 64 rows x 80 cols (gate-complete, 16 units).
// A and B both double-buffered in LDS via global_load_lds, staged ONE FULL
// ITERATION ahead; iter top = vmcnt(0) (drains iter-old DMAs, ~free) then
// s_barrier.  B image is pre-swizzled so the DMA is linear and ds_read_b128
// is bank-conflict-free.  c-state is bf16.
template <bool FIRST, bool LAST>
__global__ __launch_bounds__(512, 4) void level_kernel(
    const unsigned short* __restrict__ h_in,  // FIRST: ln_b16 table; else (2M,256) bf16
    const unsigned short* __restrict__ c_in,  // (2M,256) bf16 (unused if FIRST)
    const unsigned short* __restrict__ inpx,  // (B*15,256) bf16
    const unsigned short* __restrict__ w12p,  // packed swizzled weight images
    const float* __restrict__ bias_zp,        // (1280) packed
    unsigned short* __restrict__ h_out,       // (M,256) bf16 (if !LAST)
    unsigned short* __restrict__ c_out,       // (M,256) bf16 (if !LAST)
    float* __restrict__ state_out,            // (B,256) f32 (if LAST)
    const int* __restrict__ leaf,             // leaf ids (used if FIRST)
    int log2n, int joff) {
  __shared__ __align__(1024) char ldsA[2 * 8192];
  __shared__ __align__(1024) char ldsB[2 * 20480];
  const int tid = threadIdx.x, lane = tid & 63, wv = tid >> 6;
  const int wrow = wv >> 2, wcol = wv & 3;
  const int m0 = blockIdx.x * 128;
  const int slice = blockIdx.y;
  const int n = 1 << log2n;

  f32x4 acc[4][5];
#pragma unroll
  for (int a = 0; a < 4; ++a)
#pragma unroll
    for (int t = 0; t < 5; ++t) acc[a][t] = (f32x4){0.f, 0.f, 0.f, 0.f};

  // ---- A staging source bases (kc-invariant per thread) ----
  const int rl = wv * 16 + (lane >> 2);                // row in tile this lane stages
  const int ss = (lane & 3) ^ ((rl >> 1) & 3);         // pre-swizzled 16B chunk
  const int m = m0 + rl;
  const char* hsrc0;
  const char* hsrc1;
  if (FIRST) {
    hsrc0 = (const char*)h_in + ((size_t)leaf[2 * m] * 512 + (size_t)ss * 16);
    hsrc1 = (const char*)h_in + ((size_t)leaf[2 * m + 1] * 512 + (size_t)ss * 16);
  } else {
    hsrc0 = (const char*)h_in + ((size_t)m * 1024 + (size_t)ss * 16);
    hsrc1 = hsrc0;
  }
  const int b_ = m >> log2n, i_ = m & (n - 1);
  const char* xsrc =
      (const char*)inpx + (((size_t)b_ * 15 + joff + i_) * 512 + (size_t)ss * 16);
  char* adst = ldsA + wv * 1024;  // wave-uniform base; HW appends lane*16

  auto stageA = [&](int kc, int buf) {
    const char* src;
    if (FIRST) {
      src = (kc < 8) ? hsrc0 + kc * 64
          : (kc < 16) ? hsrc1 + (kc - 8) * 64
                      : xsrc + (kc - 16) * 64;
    } else {
      src = (kc < 16) ? hsrc0 + kc * 64 : xsrc + (kc - 16) * 64;
    }
    g2l16(src, adst + buf * 8192);
  };

  const char* imgB = (const char*)w12p + (size_t)slice * 24 * 20480;
  auto stageB = [&](int kc, int buf) {
    const char* base = imgB + (size_t)kc * 20480;
    char* db = ldsB + buf * 20480;
    for (int i = wv; i < 20; i += 8)
      g2l16(base + i * 1024 + lane * 16, db + i * 1024);
  };

  // ---- LDS read offsets (swizzle invariant under +16 rows/cols => imm offsets) ----
  const int ar = wrow * 64 + (lane & 15);
  const int aoff = ar * 64 + (((lane >> 4) ^ ((ar >> 1) & 3)) << 4);
  const int bn = wcol * 80 + (lane & 15);
  const int boff = bn * 64 + (((lane >> 4) ^ ((bn >> 1) & 3)) << 4);

  // Prologue: stage tile 0 into buffer 0.
  stageA(0, 0);
  stageB(0, 0);

  for (int kc = 0; kc < 24; ++kc) {
    // Drain own DMAs issued LAST iteration (~400cy old => near-free wait),
    // then publish to all waves.
    asm volatile("s_waitcnt vmcnt(0)" ::: "memory");
    __builtin_amdgcn_s_barrier();
    // Prefetch next tile a full iteration ahead (hidden under this MFMA).
    int kn = kc + 1;
    if (kn >= 24) kn = 0;  // harmless wrap keeps code uniform
    stageA(kn, kn & 1);
    stageB(kn, kn & 1);
    const char* pA = ldsA + (kc & 1) * 8192 + aoff;
    const char* pB = ldsB + (kc & 1) * 20480 + boff;
    bf16x8 a0 = *(const bf16x8*)(pA);
    bf16x8 a1 = *(const bf16x8*)(pA + 1024);
    bf16x8 a2 = *(const bf16x8*)(pA + 2048);
    bf16x8 a3 = *(const bf16x8*)(pA + 3072);
    bf16x8 b0 = *(const bf16x8*)(pB);
    bf16x8 b1v = *(const bf16x8*)(pB + 1024);
    bf16x8 b2v = *(const bf16x8*)(pB + 2048);
    bf16x8 b3v = *(const bf16x8*)(pB + 3072);
    bf16x8 b4v = *(const bf16x8*)(pB + 4096);
    asm volatile("s_waitcnt lgkmcnt(0)" ::: "memory");
    __builtin_amdgcn_sched_barrier(0);
#pragma unroll
    for (int rt = 0; rt < 4; ++rt) {
      bf16x8 av = rt == 0 ? a0 : rt == 1 ? a1 : rt == 2 ? a2 : a3;
      acc[rt][0] = __builtin_amdgcn_mfma_f32_16x16x32_bf16(av, b0, acc[rt][0], 0, 0, 0);
      acc[rt][1] = __builtin_amdgcn_mfma_f32_16x16x32_bf16(av, b1v, acc[rt][1], 0, 0, 0);
      acc[rt][2] = __builtin_amdgcn_mfma_f32_16x16x32_bf16(av, b2v, acc[rt][2], 0, 0, 0);
      acc[rt][3] = __builtin_amdgcn_mfma_f32_16x16x32_bf16(av, b3v, acc[rt][3], 0, 0, 0);
      acc[rt][4] = __builtin_amdgcn_mfma_f32_16x16x32_bf16(av, b4v, acc[rt][4], 0, 0, 0);
    }
  }

  // ---- Epilogue: lane-local LSTM cell ----
  float bias[5];
#pragma unroll
  for (int g = 0; g < 5; ++g)
    bias[g] = bias_zp[slice * 320 + wcol * 80 + g * 16 + (lane & 15)];
  const int u = slice * 64 + wcol * 16 + (lane & 15);

#pragma unroll
  for (int rt = 0; rt < 4; ++rt) {
#pragma unroll
    for (int r = 0; r < 4; ++r) {
      int row = m0 + wrow * 64 + rt * 16 + (lane >> 4) * 4 + r;
      float za = acc[rt][0][r] + bias[0];
      float zi = acc[rt][1][r] + bias[1];
      float zo = acc[rt][4][r] + bias[4];
      float cnew = tanhfast(za) * sigf(zi);
      if (!FIRST) {
        float zf1 = acc[rt][2][r] + bias[2];
        float zf2 = acc[rt][3][r] + bias[3];
        float cl = b2f(c_in[(size_t)(2 * row) * NS + u]);
        float cr = b2f(c_in[(size_t)(2 * row + 1) * NS + u]);
        cnew += sigf(zf1) * cl + sigf(zf2) * cr;
      }
      float hnew = sigf(zo) * tanhfast(cnew);
      if (LAST) {
        state_out[(size_t)row * NS + u] = hnew;
      } else {
        h_out[(size_t)row * NS + u] = bf16b(hnew);
        c_out[(size_t)row * NS + u] = bf16b(cnew);
      }
    }
  }
}

// ---------------- Final head: relu([state|action] @ fc_W + fc_b) @ out_W + out_b ----------------
__global__ __launch_bounds__(256) void fc_kernel(
    const float* __restrict__ state, const float* __restrict__ ln_f32,
    const int* __restrict__ action_ids, const float* __restrict__ fcW,
    const float* __restrict__ fcb, const float* __restrict__ outW,
    const float* __restrict__ outb, float* __restrict__ out) {
  __shared__ float xt[32][512];
  const int tid = threadIdx.x, lane = tid & 63, wv = tid >> 6;
  const int m0 = blockIdx.x * 32;
  for (int idx = tid; idx < 32 * 256; idx += 256) {
    int r = idx >> 8, c = idx & 255;
    xt[r][c] = state[(size_t)(m0 + r) * NS + c];
    xt[r][256 + c] = ln_f32[(size_t)action_ids[m0 + r] * NS + c];
  }
  __syncthreads();
  float y[8][4];
#pragma unroll
  for (int r = 0; r < 8; ++r)
#pragma unroll
    for (int j = 0; j < 4; ++j) y[r][j] = 0.f;
  const int rbase = wv * 8;
  for (int k = 0; k < 512; ++k) {
    float4 w = *(const float4*)(fcW + (size_t)k * NS + lane * 4);
#pragma unroll
    for (int r = 0; r < 8; ++r) {
      float xv = xt[rbase + r][k];
      y[r][0] += xv * w.x; y[r][1] += xv * w.y;
      y[r][2] += xv * w.z; y[r][3] += xv * w.w;
    }
  }
  float4 ow = *(const float4*)(outW + lane * 4);
  float4 fb = *(const float4*)(fcb + lane * 4);
#pragma unroll
  for (int r = 0; r < 8; ++r) {
    float p = fmaxf(y[r][0] + fb.x, 0.f) * ow.x + fmaxf(y[r][1] + fb.y, 0.f) * ow.y +
              fmaxf(y[r][2] + fb.z, 0.f) * ow.z + fmaxf(y[r][3] + fb.w, 0.f) * ow.w;
    for (int o = 1; o < 64; o <<= 1) p += __shfl_xor(p, o);
    if (lane == 0) out[m0 + rbase + r] = p + outb[0];
  }
}

extern "C" void kernel_launch(void* const* d_in, const int* in_sizes, int n_in,
                              void* d_out, int out_size, void* d_ws, size_t ws_size,
                              hipStream_t stream) {
  const int* leaf_ids = (const int*)d_in[0];
  const int* action_ids = (const int*)d_in[1];
  const float* join_cols = (const float*)d_in[2];
  const float* emb = (const float*)d_in[3];
  const float* ln_g = (const float*)d_in[4];
  const float* ln_b = (const float*)d_in[5];
  const float* jc_W = (const float*)d_in[6];
  const float* jc_b = (const float*)d_in[7];
  const float* W1 = (const float*)d_in[8];
  const float* b1 = (const float*)d_in[9];
  const float* W2 = (const float*)d_in[10];
  const float* b2 = (const float*)d_in[11];
  const float* W0 = (const float*)d_in[12];
  const float* b0 = (const float*)d_in[13];
  const float* fc_W = (const float*)d_in[14];
  const float* fc_b = (const float*)d_in[15];
  const float* out_W = (const float*)d_in[16];
  const float* out_b = (const float*)d_in[17];

  char* ws = (char*)d_ws;
  size_t o = 0;
  auto alloc = [&](size_t bytes) {
    size_t r = o;
    o += (bytes + 255) & ~(size_t)255;
    return r;
  };
  float* ln_f32 = (float*)(ws + alloc((size_t)NT * NS * 4));
  unsigned short* ln_b16 = (unsigned short*)(ws + alloc((size_t)NT * NS * 2));
  unsigned short* w12p = (unsigned short*)(ws + alloc((size_t)4 * 24 * 20480));
  float* bias_zp = (float*)(ws + alloc((size_t)NS5 * 4));
  unsigned short* inpx = (unsigned short*)(ws + alloc((size_t)NROWS_JC * NS * 2));
  unsigned short* hX = (unsigned short*)(ws + alloc((size_t)NB * 8 * NS * 2));
  unsigned short* hY = (unsigned short*)(ws + alloc((size_t)NB * 4 * NS * 2));
  unsigned short* cX = (unsigned short*)(ws + alloc((size_t)NB * 8 * NS * 2));
  unsigned short* cY = (unsigned short*)(ws + alloc((size_t)NB * 4 * NS * 2));
  float* state = (float*)(ws + alloc((size_t)NB * NS * 4));
  (void)ws_size; (void)in_sizes; (void)n_in; (void)out_size;

  ln_kernel<<<NT, 256, 0, stream>>>(emb, ln_g, ln_b, ln_f32, ln_b16);
  pack_w12<<<480, 256, 0, stream>>>(W1, W2, W0, w12p);
  bias_kernel<<<5, 256, 0, stream>>>(b1, b2, b0, bias_zp);
  inputx_kernel<<<NROWS_JC / 4, 256, 0, stream>>>(join_cols, jc_W, jc_b, inpx);

  // Level 0: n=8, off=0, M=65536
  level_kernel<true, false><<<dim3(512, 4), 512, 0, stream>>>(
      ln_b16, nullptr, inpx, w12p, bias_zp, hX, cX, nullptr, leaf_ids, 3, 0);
  // Level 1: n=4, off=8, M=32768
  level_kernel<false, false><<<dim3(256, 4), 512, 0, stream>>>(
      hX, cX, inpx, w12p, bias_zp, hY, cY, nullptr, leaf_ids, 2, 8);
  // Level 2: n=2, off=12, M=16384
  level_kernel<false, false><<<dim3(128, 4), 512, 0, stream>>>(
      hY, cY, inpx, w12p, bias_zp, hX, cX, nullptr, leaf_ids, 1, 12);
  // Level 3: n=1, off=14, M=8192 -> state (f32)
  level_kernel<false, true><<<dim3(64, 4), 512, 0, stream>>>(
      hX, cX, inpx, w12p, bias_zp, nullptr, nullptr, state, leaf_ids, 0, 14);

  fc_kernel<<<NB / 32, 256, 0, stream>>>(state, ln_f32, action_ids, fc_W, fc_b,
                                         out_W, out_b, (float*)d_out);
}

// Round 6
// 441.901 us; speedup vs baseline: 1.2442x; 1.1619x over previous
//
#include <hip/hip_runtime.h>
#include <hip/hip_bf16.h>
#include <stdint.h>

// Problem constants
#define NB 8192     // B
#define NL 16       // L
#define NS 256      // S
#define NT 1000     // T
#define NC 500      // C
#define NS5 1280    // 5*S
#define NROWS_JC (NB*15)   // 122880 join rows / inputx rows

typedef __attribute__((ext_vector_type(8))) short bf16x8;
typedef __attribute__((ext_vector_type(4))) float f32x4;

typedef __attribute__((address_space(1))) const void gas_void;
typedef __attribute__((address_space(3))) void las_void;

__device__ __forceinline__ void g2l16(const void* g, void* l) {
  __builtin_amdgcn_global_load_lds((gas_void*)g, (las_void*)l, 16, 0, 0);
}

__device__ __forceinline__ float sigf(float x) { return 1.f / (1.f + __expf(-x)); }
__device__ __forceinline__ float tanhfast(float x) {
  float e = __expf(2.f * fabsf(x));
  float t = 1.f - 2.f / (e + 1.f);
  return copysignf(t, x);
}
__device__ __forceinline__ unsigned short bf16b(float x) {
  __hip_bfloat16 h = __float2bfloat16(x);
  return *reinterpret_cast<unsigned short*>(&h);
}
__device__ __forceinline__ float b2f(unsigned short v) {
  union { unsigned u; float f; } x;
  x.u = (unsigned)v << 16;
  return x.f;
}

// Gate-interleaved packed-column decode (quarter-based so each col-wave is
// gate-complete for 16 units).
// packed col pc = slice*320 + q*80 + g*16 + u16
//   -> unit U = slice*64 + q*16 + u16, gate g, orig col = g*256 + U
__device__ __forceinline__ int origcol(int slice, int nc) {
  int q = nc / 80, rem = nc % 80;
  int g = rem / 16, u16 = rem % 16;
  int U = slice * 64 + q * 16 + u16;
  return g * 256 + U;
}

// ---------------- LayerNorm of the embedding table ----------------
__global__ __launch_bounds__(256) void ln_kernel(
    const float* __restrict__ emb, const float* __restrict__ g,
    const float* __restrict__ b, float* __restrict__ of32,
    unsigned short* __restrict__ ob16) {
  int t = blockIdx.x;
  int i = threadIdx.x;
  int lane = i & 63, wv = i >> 6;
  float x = emb[t * NS + i];
  float s = x, s2 = x * x;
  for (int o = 1; o < 64; o <<= 1) {
    s += __shfl_xor(s, o);
    s2 += __shfl_xor(s2, o);
  }
  __shared__ float rs[4], rs2[4];
  if (lane == 0) { rs[wv] = s; rs2[wv] = s2; }
  __syncthreads();
  float S = rs[0] + rs[1] + rs[2] + rs[3];
  float S2 = rs2[0] + rs2[1] + rs2[2] + rs2[3];
  float mu = S * (1.f / NS);
  float var = S2 * (1.f / NS) - mu * mu;
  float y = (x - mu) * rsqrtf(var + 1e-5f) * g[i] + b[i];
  of32[t * NS + i] = y;
  ob16[t * NS + i] = bf16b(y);
}

// ---------------- Pack [W1;W2;W0] into per-K-chunk LINEAR images ----------------
// image: [slice(4)][kc(24)][20480 bytes]; value (nc, k=kc*32+kg*8+j) at byte
//   nc*64 + kg*16 + j*2.  (B is consumed via per-lane register loads, so no
//   LDS swizzle; each wave's 5 fragment loads are coalesced 1KB regions.)
__global__ __launch_bounds__(256) void pack_w12(
    const float* __restrict__ W1, const float* __restrict__ W2,
    const float* __restrict__ W0, unsigned short* __restrict__ out) {
  int e = blockIdx.x * 256 + threadIdx.x;  // 4*24*320*4 = 122880 slots
  if (e >= 4 * 24 * 320 * 4) return;
  int kg = e & 3;
  int r = e >> 2;
  int nc = r % 320; r /= 320;
  int kc = r % 24;
  int slice = r / 24;
  int oc = origcol(slice, nc);
  int kbase = kc * 32 + kg * 8;
  unsigned short tmp[8];
#pragma unroll
  for (int j = 0; j < 8; ++j) {
    int k = kbase + j;
    float x;
    if (k < 256) x = W1[(size_t)k * NS5 + oc];
    else if (k < 512) x = W2[(size_t)(k - 256) * NS5 + oc];
    else x = W0[(size_t)(k - 512) * NS5 + oc];
    tmp[j] = bf16b(x);
  }
  ushort4 v0 = make_ushort4(tmp[0], tmp[1], tmp[2], tmp[3]);
  ushort4 v1 = make_ushort4(tmp[4], tmp[5], tmp[6], tmp[7]);
  size_t dst = (size_t)(slice * 24 + kc) * 20480 + (size_t)nc * 64 + kg * 16;
  *(ushort4*)((char*)out + dst) = v0;
  *(ushort4*)((char*)out + dst + 8) = v1;
}

// ---------------- Combined z-bias (b1+b2+b0), packed columns ----------------
__global__ __launch_bounds__(256) void bias_kernel(
    const float* __restrict__ b1, const float* __restrict__ b2,
    const float* __restrict__ b0, float* __restrict__ bias_zp) {
  int pc = blockIdx.x * 256 + threadIdx.x;
  if (pc >= NS5) return;
  int slice = pc / 320, nc = pc % 320;
  int oc = origcol(slice, nc);
  bias_zp[pc] = b1[oc] + b2[oc] + b0[oc];
}

// ---------------- Sparse join: inputx = join_cols @ jc_W + jc_b ----------------
__global__ __launch_bounds__(256) void inputx_kernel(
    const float* __restrict__ jc, const float* __restrict__ jcW,
    const float* __restrict__ jcb, unsigned short* __restrict__ outp) {
  int wv = threadIdx.x >> 6, lane = threadIdx.x & 63;
  size_t row = (size_t)blockIdx.x * 4 + wv;  // < 122880
  const float* jr = jc + row * NC;
  // row*NC*4 = row*2000 bytes, multiple of 16 -> float4-aligned.
  float4 v0 = *(const float4*)(jr + lane * 4);           // cols 0..255
  float4 v1 = make_float4(0.f, 0.f, 0.f, 0.f);           // cols 256..499
  if (lane < 61) v1 = *(const float4*)(jr + 256 + lane * 4);
  const float4 jb = *(const float4*)(jcb + lane * 4);
  float a0 = jb.x, a1 = jb.y, a2 = jb.z, a3 = jb.w;

#define GATHER_MASK(val, cbase)                                       \
  {                                                                   \
    unsigned long long m = __ballot((val) != 0.f);                    \
    while (m) {                                                       \
      int l = __ffsll(m) - 1;                                         \
      m &= m - 1;                                                     \
      int c = (cbase) + l * 4;                                        \
      const float4 w = *(const float4*)(jcW + (size_t)c * NS + lane * 4); \
      a0 += w.x; a1 += w.y; a2 += w.z; a3 += w.w;                     \
    }                                                                 \
  }
  GATHER_MASK(v0.x, 0) GATHER_MASK(v0.y, 1) GATHER_MASK(v0.z, 2) GATHER_MASK(v0.w, 3)
  GATHER_MASK(v1.x, 256) GATHER_MASK(v1.y, 257) GATHER_MASK(v1.z, 258) GATHER_MASK(v1.w, 259)
#undef GATHER_MASK

  ushort4 o;
  o.x = bf16b(a0); o.y = bf16b(a1); o.z = bf16b(a2); o.w = bf16b(a3);
  *(ushort4*)(outp + row * NS + lane * 4) = o;
}

// ---------------- Fused tree-level GEMM + LSTM cell ----------------
// z[m][pc] = sum_k A[m][k]*Bw[k][pc],  A row m = [h[2m] | h[2m+1] | inputx(m)] (768)
// Block: 64 rows x 320 packed cols (one slice), 4 waves as 1 row-group x 4
// col-groups; wave tile = 64 rows x 80 cols (gate-complete, 16 units).
// A: LDS, K-step 64, double-buffered via global_load_lds (12 barriers total).
// B: registers from the L2-resident packed image, rotating prefetch issued one
// MFMA-cluster ahead, so every B-wait retires cluster-old loads (never fresh).
//
// ORDER DISCIPLINE (fixes R5's race): stageA's 2 DMAs are pinned as the OLDEST
// VMEM ops of the iteration via sched_barrier(0) right after issue.  vmcnt
// retires in issue order, so the end-of-iter vmcnt(5) (<=5 outstanding = the 5
// newest bcur loads) PROVABLY retires both A-DMAs before the s_barrier.
template <bool FIRST, bool LAST>
__global__ __launch_bounds__(256, 2) void level_kernel(
    const unsigned short* __restrict__ h_in,  // FIRST: ln_b16 table; else (2M,256) bf16
    const unsigned short* __restrict__ c_in,  // (2M,256) bf16 (unused if FIRST)
    const unsigned short* __restrict__ inpx,  // (B*15,256) bf16
    const unsigned short* __restrict__ w12p,  // packed linear weight images
    const float* __restrict__ bias_zp,        // (1280) packed
    unsigned short* __restrict__ h_out,       // (M,256) bf16 (if !LAST)
    unsigned short* __restrict__ c_out,       // (M,256) bf16 (if !LAST)
    float* __restrict__ state_out,            // (B,256) f32 (if LAST)
    const int* __restrict__ leaf,             // leaf ids (used if FIRST)
    int log2n, int joff) {
  __shared__ __align__(1024) char ldsA[2 * 8192];
  const int tid = threadIdx.x, lane = tid & 63, wv = tid >> 6;  // wv = wcol 0..3
  const int m0 = blockIdx.x * 64;
  const int slice = blockIdx.y;
  const int n = 1 << log2n;

  f32x4 acc[4][5];
#pragma unroll
  for (int a = 0; a < 4; ++a)
#pragma unroll
    for (int t = 0; t < 5; ++t) acc[a][t] = (f32x4){0.f, 0.f, 0.f, 0.f};

  // ---- A staging source bases (kc-invariant per thread) ----
  const int rl = wv * 16 + (lane >> 2);                // row 0..63 this lane stages
  const int ss = (lane & 3) ^ ((rl >> 1) & 3);         // pre-swizzled 16B chunk
  const int m = m0 + rl;
  const char* hsrc0;
  const char* hsrc1;
  if (FIRST) {
    hsrc0 = (const char*)h_in + ((size_t)leaf[2 * m] * 512 + (size_t)ss * 16);
    hsrc1 = (const char*)h_in + ((size_t)leaf[2 * m + 1] * 512 + (size_t)ss * 16);
  } else {
    hsrc0 = (const char*)h_in + ((size_t)m * 1024 + (size_t)ss * 16);
    hsrc1 = hsrc0;
  }
  const int b_ = m >> log2n, i_ = m & (n - 1);
  const char* xsrc =
      (const char*)inpx + (((size_t)b_ * 15 + joff + i_) * 512 + (size_t)ss * 16);
  char* adst = ldsA + wv * 1024;  // wave-uniform base; HW appends lane*16

  auto srcA = [&](int kc) -> const char* {
    if (FIRST) {
      return (kc < 8) ? hsrc0 + kc * 64
           : (kc < 16) ? hsrc1 + (kc - 8) * 64
                       : xsrc + (kc - 16) * 64;
    }
    return (kc < 16) ? hsrc0 + kc * 64 : xsrc + (kc - 16) * 64;
  };
  auto stageA = [&](int kt, int buf) {  // stages kc = 2kt, 2kt+1 (2 DMAs)
    g2l16(srcA(2 * kt), adst + buf * 8192);
    g2l16(srcA(2 * kt + 1), adst + buf * 8192 + 4096);
  };

  // ---- LDS A-read offset (swz indep of rt since rt*16 ≡ 0 mod 8) ----
  const int aoff = (lane & 15) * 64 + (((lane >> 4) ^ ((lane >> 1) & 3)) << 4);
  // ---- B global base: 5 coalesced 1KB wave-fragments per kc ----
  const char* gB = (const char*)w12p + (size_t)slice * 24 * 20480 +
                   (size_t)(wv * 80 + (lane & 15)) * 64 + (size_t)(lane >> 4) * 16;

  bf16x8 bcur[5], bnxt[5];
  auto loadB = [&](int kc, bf16x8* dst) {
    const char* gk = gB + (size_t)kc * 20480;
#pragma unroll
    for (int g = 0; g < 5; ++g) dst[g] = *(const bf16x8*)(gk + g * 1024);
  };

  // Prologue: tile 0 into buf 0, B(0) into regs; full drain once, then go.
  stageA(0, 0);
  loadB(0, bcur);
  asm volatile("s_waitcnt vmcnt(0)" ::: "memory");
  __builtin_amdgcn_s_barrier();

  for (int kt = 0; kt < 12; ++kt) {
    const int buf = kt & 1;
    // Prefetch next A K-tile; PIN as the iteration's oldest VMEM ops.
    stageA(kt < 11 ? kt + 1 : 11, buf ^ 1);
    __builtin_amdgcn_sched_barrier(0);
    // Prefetch B for cluster 2 (one cluster ahead).
    loadB(2 * kt + 1, bnxt);
    const char* pA = ldsA + buf * 8192 + aoff;
    bf16x8 a0 = *(const bf16x8*)(pA);
    bf16x8 a1 = *(const bf16x8*)(pA + 1024);
    bf16x8 a2 = *(const bf16x8*)(pA + 2048);
    bf16x8 a3 = *(const bf16x8*)(pA + 3072);
    // Cluster 1: kc = 2kt, B = bcur (loaded one cluster ago -> wait is free).
#pragma unroll
    for (int g = 0; g < 5; ++g) {
      acc[0][g] = __builtin_amdgcn_mfma_f32_16x16x32_bf16(a0, bcur[g], acc[0][g], 0, 0, 0);
      acc[1][g] = __builtin_amdgcn_mfma_f32_16x16x32_bf16(a1, bcur[g], acc[1][g], 0, 0, 0);
      acc[2][g] = __builtin_amdgcn_mfma_f32_16x16x32_bf16(a2, bcur[g], acc[2][g], 0, 0, 0);
      acc[3][g] = __builtin_amdgcn_mfma_f32_16x16x32_bf16(a3, bcur[g], acc[3][g], 0, 0, 0);
    }
    // Prefetch B for next iteration's cluster 1.
    loadB(2 * kt + 2 < 24 ? 2 * kt + 2 : 0, bcur);
    bf16x8 c0 = *(const bf16x8*)(pA + 4096);
    bf16x8 c1 = *(const bf16x8*)(pA + 5120);
    bf16x8 c2 = *(const bf16x8*)(pA + 6144);
    bf16x8 c3 = *(const bf16x8*)(pA + 7168);
    // Cluster 2: kc = 2kt+1, B = bnxt (issued one cluster ago).
#pragma unroll
    for (int g = 0; g < 5; ++g) {
      acc[0][g] = __builtin_amdgcn_mfma_f32_16x16x32_bf16(c0, bnxt[g], acc[0][g], 0, 0, 0);
      acc[1][g] = __builtin_amdgcn_mfma_f32_16x16x32_bf16(c1, bnxt[g], acc[1][g], 0, 0, 0);
      acc[2][g] = __builtin_amdgcn_mfma_f32_16x16x32_bf16(c2, bnxt[g], acc[2][g], 0, 0, 0);
      acc[3][g] = __builtin_amdgcn_mfma_f32_16x16x32_bf16(c3, bnxt[g], acc[3][g], 0, 0, 0);
    }
    // Retire the A-DMAs (oldest VMEM ops of this iteration; vmcnt retires in
    // issue order, so <=5 outstanding == only the 5 bcur prefetch loads).
    __builtin_amdgcn_sched_barrier(0);
    asm volatile("s_waitcnt vmcnt(5)" ::: "memory");
    __builtin_amdgcn_sched_barrier(0);
    __builtin_amdgcn_s_barrier();
  }

  // ---- Epilogue: lane-local LSTM cell ----
  float bias[5];
#pragma unroll
  for (int g = 0; g < 5; ++g)
    bias[g] = bias_zp[slice * 320 + wv * 80 + g * 16 + (lane & 15)];
  const int u = slice * 64 + wv * 16 + (lane & 15);

#pragma unroll
  for (int rt = 0; rt < 4; ++rt) {
#pragma unroll
    for (int r = 0; r < 4; ++r) {
      int row = m0 + rt * 16 + (lane >> 4) * 4 + r;
      float za = acc[rt][0][r] + bias[0];
      float zi = acc[rt][1][r] + bias[1];
      float zo = acc[rt][4][r] + bias[4];
      float cnew = tanhfast(za) * sigf(zi);
      if (!FIRST) {
        float zf1 = acc[rt][2][r] + bias[2];
        float zf2 = acc[rt][3][r] + bias[3];
        float cl = b2f(c_in[(size_t)(2 * row) * NS + u]);
        float cr = b2f(c_in[(size_t)(2 * row + 1) * NS + u]);
        cnew += sigf(zf1) * cl + sigf(zf2) * cr;
      }
      float hnew = sigf(zo) * tanhfast(cnew);
      if (LAST) {
        state_out[(size_t)row * NS + u] = hnew;
      } else {
        h_out[(size_t)row * NS + u] = bf16b(hnew);
        c_out[(size_t)row * NS + u] = bf16b(cnew);
      }
    }
  }
}

// ---------------- Final head: relu([state|action] @ fc_W + fc_b) @ out_W + out_b ----------------
__global__ __launch_bounds__(256) void fc_kernel(
    const float* __restrict__ state, const float* __restrict__ ln_f32,
    const int* __restrict__ action_ids, const float* __restrict__ fcW,
    const float* __restrict__ fcb, const float* __restrict__ outW,
    const float* __restrict__ outb, float* __restrict__ out) {
  __shared__ float xt[32][512];
  const int tid = threadIdx.x, lane = tid & 63, wv = tid >> 6;
  const int m0 = blockIdx.x * 32;
  for (int idx = tid; idx < 32 * 256; idx += 256) {
    int r = idx >> 8, c = idx & 255;
    xt[r][c] = state[(size_t)(m0 + r) * NS + c];
    xt[r][256 + c] = ln_f32[(size_t)action_ids[m0 + r] * NS + c];
  }
  __syncthreads();
  float y[8][4];
#pragma unroll
  for (int r = 0; r < 8; ++r)
#pragma unroll
    for (int j = 0; j < 4; ++j) y[r][j] = 0.f;
  const int rbase = wv * 8;
  for (int k = 0; k < 512; ++k) {
    float4 w = *(const float4*)(fcW + (size_t)k * NS + lane * 4);
#pragma unroll
    for (int r = 0; r < 8; ++r) {
      float xv = xt[rbase + r][k];
      y[r][0] += xv * w.x; y[r][1] += xv * w.y;
      y[r][2] += xv * w.z; y[r][3] += xv * w.w;
    }
  }
  float4 ow = *(const float4*)(outW + lane * 4);
  float4 fb = *(const float4*)(fcb + lane * 4);
#pragma unroll
  for (int r = 0; r < 8; ++r) {
    float p = fmaxf(y[r][0] + fb.x, 0.f) * ow.x + fmaxf(y[r][1] + fb.y, 0.f) * ow.y +
              fmaxf(y[r][2] + fb.z, 0.f) * ow.z + fmaxf(y[r][3] + fb.w, 0.f) * ow.w;
    for (int o = 1; o < 64; o <<= 1) p += __shfl_xor(p, o);
    if (lane == 0) out[m0 + rbase + r] = p + outb[0];
  }
}

extern "C" void kernel_launch(void* const* d_in, const int* in_sizes, int n_in,
                              void* d_out, int out_size, void* d_ws, size_t ws_size,
                              hipStream_t stream) {
  const int* leaf_ids = (const int*)d_in[0];
  const int* action_ids = (const int*)d_in[1];
  const float* join_cols = (const float*)d_in[2];
  const float* emb = (const float*)d_in[3];
  const float* ln_g = (const float*)d_in[4];
  const float* ln_b = (const float*)d_in[5];
  const float* jc_W = (const float*)d_in[6];
  const float* jc_b = (const float*)d_in[7];
  const float* W1 = (const float*)d_in[8];
  const float* b1 = (const float*)d_in[9];
  const float* W2 = (const float*)d_in[10];
  const float* b2 = (const float*)d_in[11];
  const float* W0 = (const float*)d_in[12];
  const float* b0 = (const float*)d_in[13];
  const float* fc_W = (const float*)d_in[14];
  const float* fc_b = (const float*)d_in[15];
  const float* out_W = (const float*)d_in[16];
  const float* out_b = (const float*)d_in[17];

  char* ws = (char*)d_ws;
  size_t o = 0;
  auto alloc = [&](size_t bytes) {
    size_t r = o;
    o += (bytes + 255) & ~(size_t)255;
    return r;
  };
  float* ln_f32 = (float*)(ws + alloc((size_t)NT * NS * 4));
  unsigned short* ln_b16 = (unsigned short*)(ws + alloc((size_t)NT * NS * 2));
  unsigned short* w12p = (unsigned short*)(ws + alloc((size_t)4 * 24 * 20480));
  float* bias_zp = (float*)(ws + alloc((size_t)NS5 * 4));
  unsigned short* inpx = (unsigned short*)(ws + alloc((size_t)NROWS_JC * NS * 2));
  unsigned short* hX = (unsigned short*)(ws + alloc((size_t)NB * 8 * NS * 2));
  unsigned short* hY = (unsigned short*)(ws + alloc((size_t)NB * 4 * NS * 2));
  unsigned short* cX = (unsigned short*)(ws + alloc((size_t)NB * 8 * NS * 2));
  unsigned short* cY = (unsigned short*)(ws + alloc((size_t)NB * 4 * NS * 2));
  float* state = (float*)(ws + alloc((size_t)NB * NS * 4));
  (void)ws_size; (void)in_sizes; (void)n_in; (void)out_size;

  ln_kernel<<<NT, 256, 0, stream>>>(emb, ln_g, ln_b, ln_f32, ln_b16);
  pack_w12<<<480, 256, 0, stream>>>(W1, W2, W0, w12p);
  bias_kernel<<<5, 256, 0, stream>>>(b1, b2, b0, bias_zp);
  inputx_kernel<<<NROWS_JC / 4, 256, 0, stream>>>(join_cols, jc_W, jc_b, inpx);

  // Level 0: n=8, off=0, M=65536
  level_kernel<true, false><<<dim3(1024, 4), 256, 0, stream>>>(
      ln_b16, nullptr, inpx, w12p, bias_zp, hX, cX, nullptr, leaf_ids, 3, 0);
  // Level 1: n=4, off=8, M=32768
  level_kernel<false, false><<<dim3(512, 4), 256, 0, stream>>>(
      hX, cX, inpx, w12p, bias_zp, hY, cY, nullptr, leaf_ids, 2, 8);
  // Level 2: n=2, off=12, M=16384
  level_kernel<false, false><<<dim3(256, 4), 256, 0, stream>>>(
      hY, cY, inpx, w12p, bias_zp, hX, cX, nullptr, leaf_ids, 1, 12);
  // Level 3: n=1, off=14, M=8192 -> state (f32)
  level_kernel<false, true><<<dim3(128, 4), 256, 0, stream>>>(
      hX, cX, inpx, w12p, bias_zp, nullptr, nullptr, state, leaf_ids, 0, 14);

  fc_kernel<<<NB / 32, 256, 0, stream>>>(state, ln_f32, action_ids, fc_W, fc_b,
                                         out_W, out_b, (float*)d_out);
}